// Round 2
// baseline (1164.624 us; speedup 1.0000x reference)
//
#include <hip/hip_runtime.h>
#include <stdint.h>

#define N_NODES 50000
#define N_EDGES 600000
#define DIM 128
#define N_TILES (N_EDGES / 64)

typedef __attribute__((ext_vector_type(8))) short bf16x8;
typedef __attribute__((ext_vector_type(4))) float f32x4;
typedef __attribute__((ext_vector_type(4))) unsigned int u32x4;

__device__ inline unsigned short f2bf(float f) {
  unsigned u = __builtin_bit_cast(unsigned, f);
  unsigned r = 0x7fffu + ((u >> 16) & 1u);
  return (unsigned short)((u + r) >> 16);
}

// ---- LDS staging helpers (swizzled bf16 tiles, row stride 256 B) ----
// swizzle: byte_off_in_row ^= ((row&7)<<4) -- kills the 16-way bank conflict
// on ds_read_b128 across rows.

__device__ inline void stage_pack_store(char* lds, int row, int f, f32x4 v0, f32x4 v1) {
  u32x4 q;
  q[0] = (unsigned)f2bf(v0[0]) | ((unsigned)f2bf(v0[1]) << 16);
  q[1] = (unsigned)f2bf(v0[2]) | ((unsigned)f2bf(v0[3]) << 16);
  q[2] = (unsigned)f2bf(v1[0]) | ((unsigned)f2bf(v1[1]) << 16);
  q[3] = (unsigned)f2bf(v1[2]) | ((unsigned)f2bf(v1[3]) << 16);
  int byte = (f * 16) ^ ((row & 7) << 4);
  *(u32x4*)(lds + row * 256 + byte) = q;
}

// stage a [64 x 128] f32 tile (consecutive rows) -> LDS bf16
__device__ inline void stage_tile_f32(const float* __restrict__ src, int row0,
                                      int nvalid, char* lds) {
#pragma unroll
  for (int it = 0; it < 4; ++it) {
    int c = it * 256 + threadIdx.x;
    int row = c >> 4, f = c & 15;
    f32x4 v0 = {0, 0, 0, 0}, v1 = {0, 0, 0, 0};
    if (row < nvalid) {
      const f32x4* p = (const f32x4*)(src + (size_t)(row0 + row) * DIM + f * 8);
      v0 = p[0]; v1 = p[1];
    }
    stage_pack_store(lds, row, f, v0, v1);
  }
}

// stage a [64 x 128] f32 tile gathered through perm -> LDS bf16
__device__ inline void stage_tile_gather(const float* __restrict__ src,
                                         const int* __restrict__ perm, int tile,
                                         char* lds) {
#pragma unroll
  for (int it = 0; it < 4; ++it) {
    int c = it * 256 + threadIdx.x;
    int row = c >> 4, f = c & 15;
    int pe = perm[tile * 64 + row];            // redundant x16, L1-broadcast
    const f32x4* p = (const f32x4*)(src + (size_t)pe * DIM + f * 8);
    stage_pack_store(lds, row, f, p[0], p[1]);
  }
}

// stage a [128 x 128] bf16 weight matrix -> LDS
__device__ inline void stage_w(const unsigned short* __restrict__ wbf, char* lds) {
#pragma unroll
  for (int it = 0; it < 8; ++it) {
    int c = it * 256 + threadIdx.x;
    int row = c >> 4, f = c & 15;
    u32x4 q = *(const u32x4*)(wbf + row * 128 + f * 8);
    int byte = (f * 16) ^ ((row & 7) << 4);
    *(u32x4*)(lds + row * 256 + byte) = q;
  }
}

__device__ inline bf16x8 read_frag(const char* lds, int row, int ks, int lane) {
  int byte = ks * 64 + ((lane >> 4) * 16);
  byte ^= ((row & 7) << 4);
  return *(const bf16x8*)(lds + row * 256 + byte);
}

// ---- K0: fp32 -> bf16 weight conversion ----
__global__ void convert_weights(const float* __restrict__ a, const float* __restrict__ b,
                                const float* __restrict__ c, const float* __restrict__ d,
                                const float* __restrict__ e5, unsigned short* __restrict__ out) {
  int i = blockIdx.x * 256 + threadIdx.x;
  if (i >= 5 * 16384) return;
  int m = i >> 14, k = i & 16383;
  const float* p = (m == 0) ? a : (m == 1) ? b : (m == 2) ? c : (m == 3) ? d : e5;
  out[i] = f2bf(p[k]);
}

// ---- CSR build: histogram, 1-block scan, bucket scatter ----
__global__ void hist_kernel(const int* __restrict__ dst, int* __restrict__ counts) {
  int i = blockIdx.x * 256 + threadIdx.x;
  if (i < N_EDGES) atomicAdd(&counts[dst[i]], 1);
}

__global__ __launch_bounds__(1024) void scan_kernel(const int* __restrict__ counts,
                                                    int* __restrict__ offsets) {
  __shared__ int part[1024];
  const int CH = 49;                       // 1024*49 = 50176 >= 50000
  int t = threadIdx.x;
  int base = t * CH;
  int s = 0;
  for (int k = 0; k < CH; ++k) {
    int i = base + k;
    if (i < N_NODES) s += counts[i];
  }
  part[t] = s;
  __syncthreads();
  for (int off = 1; off < 1024; off <<= 1) {
    int v = part[t];
    int u = (t >= off) ? part[t - off] : 0;
    __syncthreads();
    part[t] = v + u;
    __syncthreads();
  }
  int run = (t == 0) ? 0 : part[t - 1];
  for (int k = 0; k < CH; ++k) {
    int i = base + k;
    if (i < N_NODES) { offsets[i] = run; run += counts[i]; }
  }
  if (t == 1023) offsets[N_NODES] = run;
}

__global__ void bucket_kernel(const int* __restrict__ dst, const int* __restrict__ offsets,
                              int* __restrict__ cursor, int* __restrict__ perm) {
  int i = blockIdx.x * 256 + threadIdx.x;
  if (i < N_EDGES) {
    int d = dst[i];
    int p = offsets[d] + atomicAdd(&cursor[d], 1);
    perm[p] = i;
  }
}

// ---- K1: node GEMMs ----
__global__ __launch_bounds__(256) void node_gemm(
    const float* __restrict__ h, const unsigned short* __restrict__ wbf,
    const float* __restrict__ Ab, const float* __restrict__ Bb,
    const float* __restrict__ Db, const float* __restrict__ Eb,
    float* __restrict__ Ah, float* __restrict__ Bh,
    float* __restrict__ Dh, float* __restrict__ Eh) {
  __shared__ __align__(16) char lds_x[64 * 256];
  __shared__ __align__(16) char lds_w[128 * 256];
  int tile = blockIdx.x * 64;
  int nvalid = N_NODES - tile; if (nvalid > 64) nvalid = 64;
  stage_tile_f32(h, tile, nvalid, lds_x);
  int lane = threadIdx.x & 63, w = threadIdx.x >> 6;
  int prow = w * 16 + (lane & 15);
  __syncthreads();
  bf16x8 a[4];
#pragma unroll
  for (int ks = 0; ks < 4; ++ks) a[ks] = read_frag(lds_x, prow, ks, lane);

  const int wmat[4] = {0, 1, 3, 4};
  float* const outs[4] = {Ah, Bh, Dh, Eh};
  const float* const biases[4] = {Ab, Bb, Db, Eb};
#pragma unroll
  for (int m = 0; m < 4; ++m) {
    __syncthreads();
    stage_w(wbf + wmat[m] * 16384, lds_w);
    __syncthreads();
    f32x4 acc[8] = {};
#pragma unroll
    for (int ct = 0; ct < 8; ++ct) {
#pragma unroll
      for (int ks = 0; ks < 4; ++ks) {
        bf16x8 b = read_frag(lds_w, ct * 16 + (lane & 15), ks, lane);
        acc[ct] = __builtin_amdgcn_mfma_f32_16x16x32_bf16(a[ks], b, acc[ct], 0, 0, 0);
      }
    }
    const float* bias = biases[m];
    float* out = outs[m];
#pragma unroll
    for (int ct = 0; ct < 8; ++ct) {
      int col = ct * 16 + (lane & 15);
      float bv = bias[col];
#pragma unroll
      for (int j = 0; j < 4; ++j) {
        int r = tile + w * 16 + (lane >> 4) * 4 + j;
        if (r < N_NODES) out[(size_t)r * DIM + col] = acc[ct][j] + bv;
      }
    }
  }
}

// ---- K2: edge phase 0 on dst-sorted edges: GEMM + sigma + merged scatter + stats ----
__global__ __launch_bounds__(256) void edge_phase0(
    const float* __restrict__ e, const int* __restrict__ src, const int* __restrict__ dst,
    const int* __restrict__ perm,
    const unsigned short* __restrict__ wbf, const float* __restrict__ Cb,
    const float* __restrict__ Bh, const float* __restrict__ Dh, const float* __restrict__ Eh,
    float* __restrict__ acc_h, float* __restrict__ acc_s,
    float* __restrict__ stat_sum, float* __restrict__ stat_sum2) {
  __shared__ __align__(16) char lds_x[64 * 256];
  __shared__ __align__(16) char lds_w[128 * 256];
  __shared__ int s_src[64], s_dst[64];
  __shared__ float s_sum[128], s_sum2[128];
  stage_w(wbf + 2 * 16384, lds_w);
  if (threadIdx.x < 128) { s_sum[threadIdx.x] = 0.f; s_sum2[threadIdx.x] = 0.f; }
  int lane = threadIdx.x & 63, w = threadIdx.x >> 6;
  int prow = w * 16 + (lane & 15);
  int rbase = w * 16 + ((lane >> 4) << 2);
  float ssumr[8] = {0, 0, 0, 0, 0, 0, 0, 0};
  float ssum2r[8] = {0, 0, 0, 0, 0, 0, 0, 0};

  for (int tile = blockIdx.x; tile < N_TILES; tile += gridDim.x) {
    __syncthreads();                           // protect lds_x / s_* reuse
    stage_tile_gather(e, perm, tile, lds_x);
    if (threadIdx.x < 64) {
      int pe = perm[tile * 64 + threadIdx.x];
      s_src[threadIdx.x] = src[pe];
      s_dst[threadIdx.x] = dst[pe];
    }
    __syncthreads();
    bf16x8 a[4];
#pragma unroll
    for (int ks = 0; ks < 4; ++ks) a[ks] = read_frag(lds_x, prow, ks, lane);
    f32x4 acc[8] = {};
#pragma unroll
    for (int ct = 0; ct < 8; ++ct) {
#pragma unroll
      for (int ks = 0; ks < 4; ++ks) {
        bf16x8 b = read_frag(lds_w, ct * 16 + (lane & 15), ks, lane);
        acc[ct] = __builtin_amdgcn_mfma_f32_16x16x32_bf16(a[ks], b, acc[ct], 0, 0, 0);
      }
    }
#pragma unroll
    for (int ct = 0; ct < 8; ++ct) {
      int col = ct * 16 + (lane & 15);
      float cbv = Cb[col];
      float am = 0.f, asg = 0.f;
      int cur = s_dst[rbase];
#pragma unroll
      for (int j = 0; j < 4; ++j) {
        int rl = rbase + j;
        int s = s_src[rl], d = s_dst[rl];
        float enew = acc[ct][j] + cbv + Dh[(size_t)s * DIM + col] + Eh[(size_t)d * DIM + col];
        float sig = 1.f / (1.f + __expf(-enew));
        float mv = Bh[(size_t)s * DIM + col] * sig;
        ssumr[ct] += enew;
        ssum2r[ct] += enew * enew;
        if (d != cur) {                        // dst run ended -> flush
          atomicAdd(acc_h + (size_t)cur * DIM + col, am);
          atomicAdd(acc_s + (size_t)cur * DIM + col, asg);
          am = 0.f; asg = 0.f; cur = d;
        }
        am += mv; asg += sig;
      }
      atomicAdd(acc_h + (size_t)cur * DIM + col, am);
      atomicAdd(acc_s + (size_t)cur * DIM + col, asg);
    }
  }
  // BN-e stats: reduce once per block
#pragma unroll
  for (int ct = 0; ct < 8; ++ct) {
    float a = ssumr[ct], b = ssum2r[ct];
    a += __shfl_xor(a, 16); a += __shfl_xor(a, 32);
    b += __shfl_xor(b, 16); b += __shfl_xor(b, 32);
    if (lane < 16) {
      atomicAdd(&s_sum[ct * 16 + (lane & 15)], a);
      atomicAdd(&s_sum2[ct * 16 + (lane & 15)], b);
    }
  }
  __syncthreads();
  if (threadIdx.x < 128) {
    atomicAdd(stat_sum + threadIdx.x, s_sum[threadIdx.x]);
    atomicAdd(stat_sum2 + threadIdx.x, s_sum2[threadIdx.x]);
  }
}

// ---- K4: edge phase 1 (original order): recompute e_new, apply BN, residual ----
__global__ __launch_bounds__(256) void edge_phase1(
    const float* __restrict__ e, const int* __restrict__ src, const int* __restrict__ dst,
    const unsigned short* __restrict__ wbf, const float* __restrict__ Cb,
    const float* __restrict__ Dh, const float* __restrict__ Eh,
    const float* __restrict__ scale_e, const float* __restrict__ shift_e,
    float* __restrict__ e_out) {
  __shared__ __align__(16) char lds_x[64 * 256];
  __shared__ __align__(16) char lds_w[128 * 256];
  __shared__ int s_src[64], s_dst[64];
  stage_w(wbf + 2 * 16384, lds_w);
  int lane = threadIdx.x & 63, w = threadIdx.x >> 6;
  int prow = w * 16 + (lane & 15);
  int rbase = w * 16 + ((lane >> 4) << 2);

  for (int tile = blockIdx.x; tile < N_TILES; tile += gridDim.x) {
    __syncthreads();
    stage_tile_f32(e, tile * 64, 64, lds_x);
    if (threadIdx.x < 64) {
      s_src[threadIdx.x] = src[tile * 64 + threadIdx.x];
      s_dst[threadIdx.x] = dst[tile * 64 + threadIdx.x];
    }
    __syncthreads();
    bf16x8 a[4];
#pragma unroll
    for (int ks = 0; ks < 4; ++ks) a[ks] = read_frag(lds_x, prow, ks, lane);
    f32x4 acc[8] = {};
#pragma unroll
    for (int ct = 0; ct < 8; ++ct) {
#pragma unroll
      for (int ks = 0; ks < 4; ++ks) {
        bf16x8 b = read_frag(lds_w, ct * 16 + (lane & 15), ks, lane);
        acc[ct] = __builtin_amdgcn_mfma_f32_16x16x32_bf16(a[ks], b, acc[ct], 0, 0, 0);
      }
    }
#pragma unroll
    for (int ct = 0; ct < 8; ++ct) {
      int col = ct * 16 + (lane & 15);
      float cbv = Cb[col];
      float sc = scale_e[col], sh = shift_e[col];
#pragma unroll
      for (int j = 0; j < 4; ++j) {
        int rl = rbase + j;
        int s = s_src[rl], d = s_dst[rl];
        float enew = acc[ct][j] + cbv + Dh[(size_t)s * DIM + col] + Eh[(size_t)d * DIM + col];
        int er = tile * 64 + rl;
        float y = enew * sc + sh;
        y = fmaxf(y, 0.f) + e[(size_t)er * DIM + col];
        e_out[(size_t)er * DIM + col] = y;
      }
    }
  }
}

// ---- node_pre: h_new pre-activation + BN-h stats ----
__global__ __launch_bounds__(256) void node_pre(
    const float* __restrict__ Ah, const float* __restrict__ acc_h,
    const float* __restrict__ acc_s, float* __restrict__ pre_out,
    float* __restrict__ stat_sum, float* __restrict__ stat_sum2) {
  __shared__ float s_sum[128], s_sum2[128];
  if (threadIdx.x < 128) { s_sum[threadIdx.x] = 0.f; s_sum2[threadIdx.x] = 0.f; }
  __syncthreads();
  const int total4 = N_NODES * DIM / 4;
  float ls[4] = {0, 0, 0, 0}, lq[4] = {0, 0, 0, 0};
  int colbase = (threadIdx.x & 31) * 4;
  for (int i = blockIdx.x * blockDim.x + threadIdx.x; i < total4;
       i += gridDim.x * blockDim.x) {
    f32x4 a = ((const f32x4*)Ah)[i];
    f32x4 mh = ((const f32x4*)acc_h)[i];
    f32x4 ms = ((const f32x4*)acc_s)[i];
    f32x4 p;
#pragma unroll
    for (int j = 0; j < 4; ++j) {
      p[j] = a[j] + mh[j] / (ms[j] + 1e-6f);
      ls[j] += p[j]; lq[j] += p[j] * p[j];
    }
    ((f32x4*)pre_out)[i] = p;
  }
#pragma unroll
  for (int j = 0; j < 4; ++j) {
    atomicAdd(&s_sum[colbase + j], ls[j]);
    atomicAdd(&s_sum2[colbase + j], lq[j]);
  }
  __syncthreads();
  if (threadIdx.x < 128) {
    atomicAdd(stat_sum + threadIdx.x, s_sum[threadIdx.x]);
    atomicAdd(stat_sum2 + threadIdx.x, s_sum2[threadIdx.x]);
  }
}

// ---- finalize BN scale/shift ----
__global__ void finalize_stats(const float* __restrict__ sum, const float* __restrict__ sum2,
                               const float* __restrict__ gamma, const float* __restrict__ beta,
                               float count, float* __restrict__ scale, float* __restrict__ shift) {
  int c = threadIdx.x;
  if (c < 128) {
    float mu = sum[c] / count;
    float var = sum2[c] / count - mu * mu;
    float inv = rsqrtf(var + 1e-5f);
    float sc = gamma[c] * inv;
    scale[c] = sc;
    shift[c] = beta[c] - mu * sc;
  }
}

// ---- node_final: h_out = h + relu(pre*scale + shift) ----
__global__ __launch_bounds__(256) void node_final(
    const float* __restrict__ h, float* __restrict__ hout,
    const float* __restrict__ scale, const float* __restrict__ shift) {
  const int total4 = N_NODES * DIM / 4;
  for (int i = blockIdx.x * blockDim.x + threadIdx.x; i < total4;
       i += gridDim.x * blockDim.x) {
    f32x4 p = ((const f32x4*)hout)[i];
    f32x4 hv = ((const f32x4*)h)[i];
    f32x4 sc4 = ((const f32x4*)scale)[i & 31];
    f32x4 sh4 = ((const f32x4*)shift)[i & 31];
    f32x4 o;
#pragma unroll
    for (int j = 0; j < 4; ++j) {
      float y = p[j] * sc4[j] + sh4[j];
      o[j] = hv[j] + fmaxf(y, 0.f);
    }
    ((f32x4*)hout)[i] = o;
  }
}

extern "C" void kernel_launch(void* const* d_in, const int* in_sizes, int n_in,
                              void* d_out, int out_size, void* d_ws, size_t ws_size,
                              hipStream_t stream) {
  const float* h   = (const float*)d_in[0];
  const float* e   = (const float*)d_in[1];
  const int*   src = (const int*)d_in[2];
  const int*   dst = (const int*)d_in[3];
  const float* Aw = (const float*)d_in[4];  const float* Ab = (const float*)d_in[5];
  const float* Bw = (const float*)d_in[6];  const float* Bb = (const float*)d_in[7];
  const float* Cw = (const float*)d_in[8];  const float* Cb = (const float*)d_in[9];
  const float* Dw = (const float*)d_in[10]; const float* Db = (const float*)d_in[11];
  const float* Ew = (const float*)d_in[12]; const float* Eb = (const float*)d_in[13];
  const float* bn_h_g = (const float*)d_in[14]; const float* bn_h_b = (const float*)d_in[15];
  const float* bn_e_g = (const float*)d_in[16]; const float* bn_e_b = (const float*)d_in[17];

  const size_t ND = (size_t)N_NODES * DIM * 4;   // 25.6 MB
  char* ws = (char*)d_ws;
  unsigned short* wbf = (unsigned short*)ws;      // 163840 B
  size_t off = 163840;
  float* Ah = (float*)(ws + off); off += ND;
  float* Bh = (float*)(ws + off); off += ND;
  float* Dh = (float*)(ws + off); off += ND;
  float* Eh = (float*)(ws + off); off += ND;
  // ---- zeroed region: acc_h, acc_s, counts, cursor, stats ----
  char* zero_base = ws + off;
  float* acc_h = (float*)(ws + off); off += ND;
  float* acc_s = (float*)(ws + off); off += ND;
  int* counts  = (int*)(ws + off);   off += 200000;   // 50000 ints
  int* cursor  = (int*)(ws + off);   off += 200000;
  float* stats = (float*)(ws + off); off += 4096;     // 1024 floats
  size_t zero_bytes = (size_t)(ws + off - zero_base);
  // ---- not zeroed ----
  int* offsets = (int*)(ws + off);   off += 200064;   // 50001 ints (padded)
  int* perm    = (int*)(ws + off);   off += 2400000;  // 600000 ints

  float* e_sum = stats,        *e_sum2 = stats + 128;
  float* h_sum = stats + 256,  *h_sum2 = stats + 384;
  float* scale_e = stats + 512, *shift_e = stats + 640;
  float* scale_h = stats + 768, *shift_h = stats + 896;

  float* hout = (float*)d_out;
  float* eout = (float*)d_out + (size_t)N_NODES * DIM;

  hipMemsetAsync(zero_base, 0, zero_bytes, stream);

  convert_weights<<<320, 256, 0, stream>>>(Aw, Bw, Cw, Dw, Ew, wbf);
  hist_kernel<<<(N_EDGES + 255) / 256, 256, 0, stream>>>(dst, counts);
  scan_kernel<<<1, 1024, 0, stream>>>(counts, offsets);
  bucket_kernel<<<(N_EDGES + 255) / 256, 256, 0, stream>>>(dst, offsets, cursor, perm);
  node_gemm<<<(N_NODES + 63) / 64, 256, 0, stream>>>(h, wbf, Ab, Bb, Db, Eb, Ah, Bh, Dh, Eh);
  edge_phase0<<<2048, 256, 0, stream>>>(e, src, dst, perm, wbf, Cb, Bh, Dh, Eh,
      acc_h, acc_s, e_sum, e_sum2);
  finalize_stats<<<1, 128, 0, stream>>>(e_sum, e_sum2, bn_e_g, bn_e_b, (float)N_EDGES,
      scale_e, shift_e);
  node_pre<<<1024, 256, 0, stream>>>(Ah, acc_h, acc_s, hout, h_sum, h_sum2);
  finalize_stats<<<1, 128, 0, stream>>>(h_sum, h_sum2, bn_h_g, bn_h_b, (float)N_NODES,
      scale_h, shift_h);
  edge_phase1<<<2048, 256, 0, stream>>>(e, src, dst, wbf, Cb, Dh, Eh,
      scale_e, shift_e, eout);
  node_final<<<1024, 256, 0, stream>>>(h, hout, scale_h, shift_h);
}

// Round 3
// 758.907 us; speedup vs baseline: 1.5346x; 1.5346x over previous
//
#include <hip/hip_runtime.h>
#include <stdint.h>

#define N_NODES 50000
#define N_EDGES 600000
#define DIM 128
#define N_TILES (N_EDGES / 64)   // 9375

typedef __attribute__((ext_vector_type(8))) short bf16x8;
typedef __attribute__((ext_vector_type(4))) float f32x4;
typedef __attribute__((ext_vector_type(4))) unsigned int u32x4;

__device__ inline unsigned short f2bf(float f) {
  unsigned u = __builtin_bit_cast(unsigned, f);
  unsigned r = 0x7fffu + ((u >> 16) & 1u);
  return (unsigned short)((u + r) >> 16);
}
__device__ inline float bf2f_lo(unsigned p) { return __builtin_bit_cast(float, p << 16); }
__device__ inline float bf2f_hi(unsigned p) { return __builtin_bit_cast(float, p & 0xffff0000u); }

// ---- LDS staging (swizzled bf16 tiles, row stride 256 B) ----
__device__ inline void stage_pack_store(char* lds, int row, int f, f32x4 v0, f32x4 v1) {
  u32x4 q;
  q[0] = (unsigned)f2bf(v0[0]) | ((unsigned)f2bf(v0[1]) << 16);
  q[1] = (unsigned)f2bf(v0[2]) | ((unsigned)f2bf(v0[3]) << 16);
  q[2] = (unsigned)f2bf(v1[0]) | ((unsigned)f2bf(v1[1]) << 16);
  q[3] = (unsigned)f2bf(v1[2]) | ((unsigned)f2bf(v1[3]) << 16);
  int byte = (f * 16) ^ ((row & 7) << 4);
  *(u32x4*)(lds + row * 256 + byte) = q;
}

__device__ inline void stage_tile_f32(const float* __restrict__ src, int row0,
                                      int nvalid, char* lds) {
#pragma unroll
  for (int it = 0; it < 4; ++it) {
    int c = it * 256 + threadIdx.x;
    int row = c >> 4, f = c & 15;
    f32x4 v0 = {0, 0, 0, 0}, v1 = {0, 0, 0, 0};
    if (row < nvalid) {
      const f32x4* p = (const f32x4*)(src + (size_t)(row0 + row) * DIM + f * 8);
      v0 = p[0]; v1 = p[1];
    }
    stage_pack_store(lds, row, f, v0, v1);
  }
}

__device__ inline void stage_w(const unsigned short* __restrict__ wbf, char* lds) {
#pragma unroll
  for (int it = 0; it < 8; ++it) {
    int c = it * 256 + threadIdx.x;
    int row = c >> 4, f = c & 15;
    u32x4 q = *(const u32x4*)(wbf + row * 128 + f * 8);
    int byte = (f * 16) ^ ((row & 7) << 4);
    *(u32x4*)(lds + row * 256 + byte) = q;
  }
}

__device__ inline bf16x8 read_frag(const char* lds, int row, int ks, int lane) {
  int byte = ks * 64 + ((lane >> 4) * 16);
  byte ^= ((row & 7) << 4);
  return *(const bf16x8*)(lds + row * 256 + byte);
}

// ---- K0: fp32 -> bf16 weights ----
__global__ void convert_weights(const float* __restrict__ a, const float* __restrict__ b,
                                const float* __restrict__ c, const float* __restrict__ d,
                                const float* __restrict__ e5, unsigned short* __restrict__ out) {
  int i = blockIdx.x * 256 + threadIdx.x;
  if (i >= 5 * 16384) return;
  int m = i >> 14, k = i & 16383;
  const float* p = (m == 0) ? a : (m == 1) ? b : (m == 2) ? c : (m == 3) ? d : e5;
  out[i] = f2bf(p[k]);
}

// ---- CSR build ----
__global__ void hist_kernel(const int* __restrict__ dst, int* __restrict__ counts) {
  int i = blockIdx.x * 256 + threadIdx.x;
  if (i < N_EDGES) atomicAdd(&counts[dst[i]], 1);
}

__global__ __launch_bounds__(1024) void scan_kernel(const int* __restrict__ counts,
                                                    int* __restrict__ offsets) {
  __shared__ int part[1024];
  const int CH = 49;
  int t = threadIdx.x;
  int base = t * CH;
  int s = 0;
  for (int k = 0; k < CH; ++k) {
    int i = base + k;
    if (i < N_NODES) s += counts[i];
  }
  part[t] = s;
  __syncthreads();
  for (int off = 1; off < 1024; off <<= 1) {
    int v = part[t];
    int u = (t >= off) ? part[t - off] : 0;
    __syncthreads();
    part[t] = v + u;
    __syncthreads();
  }
  int run = (t == 0) ? 0 : part[t - 1];
  for (int k = 0; k < CH; ++k) {
    int i = base + k;
    if (i < N_NODES) { offsets[i] = run; run += counts[i]; }
  }
  if (t == 1023) offsets[N_NODES] = run;
}

__global__ void bucket_kernel(const int* __restrict__ dst, const int* __restrict__ offsets,
                              int* __restrict__ cursor, int* __restrict__ perm) {
  int i = blockIdx.x * 256 + threadIdx.x;
  if (i < N_EDGES) {
    int d = dst[i];
    int p = offsets[d] + atomicAdd(&cursor[d], 1);
    perm[p] = i;
  }
}

// ---- K1: node GEMMs. Ah fp32; Bh/Dh/Eh bf16 (gather tables) ----
__global__ __launch_bounds__(256) void node_gemm(
    const float* __restrict__ h, const unsigned short* __restrict__ wbf,
    const float* __restrict__ Ab, const float* __restrict__ Bb,
    const float* __restrict__ Db, const float* __restrict__ Eb,
    float* __restrict__ Ah, unsigned short* __restrict__ Bh,
    unsigned short* __restrict__ Dh, unsigned short* __restrict__ Eh) {
  __shared__ __align__(16) char lds_x[64 * 256];
  __shared__ __align__(16) char lds_w[128 * 256];
  int tile = blockIdx.x * 64;
  int nvalid = N_NODES - tile; if (nvalid > 64) nvalid = 64;
  stage_tile_f32(h, tile, nvalid, lds_x);
  int lane = threadIdx.x & 63, w = threadIdx.x >> 6;
  int prow = w * 16 + (lane & 15);
  __syncthreads();
  bf16x8 a[4];
#pragma unroll
  for (int ks = 0; ks < 4; ++ks) a[ks] = read_frag(lds_x, prow, ks, lane);

  const int wmat[4] = {0, 1, 3, 4};           // A,B,D,E
  unsigned short* const outs_bf[4] = {nullptr, Bh, Dh, Eh};
  const float* const biases[4] = {Ab, Bb, Db, Eb};
#pragma unroll
  for (int m = 0; m < 4; ++m) {
    __syncthreads();
    stage_w(wbf + wmat[m] * 16384, lds_w);
    __syncthreads();
    f32x4 acc[8] = {};
#pragma unroll
    for (int ct = 0; ct < 8; ++ct) {
#pragma unroll
      for (int ks = 0; ks < 4; ++ks) {
        bf16x8 b = read_frag(lds_w, ct * 16 + (lane & 15), ks, lane);
        acc[ct] = __builtin_amdgcn_mfma_f32_16x16x32_bf16(a[ks], b, acc[ct], 0, 0, 0);
      }
    }
    const float* bias = biases[m];
#pragma unroll
    for (int ct = 0; ct < 8; ++ct) {
      int col = ct * 16 + (lane & 15);
      float bv = bias[col];
#pragma unroll
      for (int j = 0; j < 4; ++j) {
        int r = tile + w * 16 + (lane >> 4) * 4 + j;
        if (r < N_NODES) {
          float v = acc[ct][j] + bv;
          if (m == 0) Ah[(size_t)r * DIM + col] = v;
          else outs_bf[m][(size_t)r * DIM + col] = f2bf(v);
        }
      }
    }
  }
}

// ---- K2: Ce = e @ C^T + Cb  -> bf16 (streams e once, grid-stride) ----
__global__ __launch_bounds__(256) void ce_gemm(
    const float* __restrict__ e, const unsigned short* __restrict__ wbf,
    const float* __restrict__ Cb, unsigned short* __restrict__ Ce) {
  __shared__ __align__(16) char lds_x[64 * 256];
  __shared__ __align__(16) char lds_w[128 * 256];
  stage_w(wbf + 2 * 16384, lds_w);
  int lane = threadIdx.x & 63, w = threadIdx.x >> 6;
  int prow = w * 16 + (lane & 15);
  for (int tile = blockIdx.x; tile < N_TILES; tile += gridDim.x) {
    __syncthreads();
    stage_tile_f32(e, tile * 64, 64, lds_x);
    __syncthreads();
    bf16x8 a[4];
#pragma unroll
    for (int ks = 0; ks < 4; ++ks) a[ks] = read_frag(lds_x, prow, ks, lane);
    f32x4 acc[8] = {};
#pragma unroll
    for (int ct = 0; ct < 8; ++ct) {
#pragma unroll
      for (int ks = 0; ks < 4; ++ks) {
        bf16x8 b = read_frag(lds_w, ct * 16 + (lane & 15), ks, lane);
        acc[ct] = __builtin_amdgcn_mfma_f32_16x16x32_bf16(a[ks], b, acc[ct], 0, 0, 0);
      }
    }
#pragma unroll
    for (int ct = 0; ct < 8; ++ct) {
      int col = ct * 16 + (lane & 15);
      float bv = Cb[col];
#pragma unroll
      for (int j = 0; j < 4; ++j) {
        int r = tile * 64 + w * 16 + (lane >> 4) * 4 + j;
        Ce[(size_t)r * DIM + col] = f2bf(acc[ct][j] + bv);
      }
    }
  }
}

// ---- K3: gather/scatter pass over dst-sorted edges. No MFMA, tiny LDS. ----
// In-place: reads Ce (bf16), writes e_new (bf16) to the same buffer.
__global__ __launch_bounds__(256) void edge_gather(
    const int* __restrict__ src, const int* __restrict__ dst, const int* __restrict__ perm,
    const unsigned short* __restrict__ Bh, const unsigned short* __restrict__ Dh,
    const unsigned short* __restrict__ Eh,
    unsigned short* __restrict__ Ce_enew,
    float* __restrict__ acc_h, float* __restrict__ acc_s,
    float* __restrict__ stat_sum, float* __restrict__ stat_sum2) {
  __shared__ int s_pe[4][64], s_src[4][64], s_dst[4][64];
  __shared__ float s_sum[128], s_sum2[128];
  if (threadIdx.x < 128) { s_sum[threadIdx.x] = 0.f; s_sum2[threadIdx.x] = 0.f; }
  int w = threadIdx.x >> 6, lane = threadIdx.x & 63;
  int sid = blockIdx.x * 4 + w;
  bool active = (sid < N_TILES);
  if (active) {
    int base = sid * 64;
    int pe = perm[base + lane];
    s_pe[w][lane] = pe;
    s_src[w][lane] = src[pe];
    s_dst[w][lane] = dst[pe];
  }
  __syncthreads();
  float sum0 = 0.f, sum1 = 0.f, q0 = 0.f, q1 = 0.f;
  if (active) {
    int cur_d = s_dst[w][0];
    unsigned ehp = *(const unsigned*)(Eh + (size_t)cur_d * DIM + 2 * lane);
    float eh0 = bf2f_lo(ehp), eh1 = bf2f_hi(ehp);
    float am0 = 0.f, am1 = 0.f, as0 = 0.f, as1 = 0.f;
#pragma unroll 4
    for (int j = 0; j < 64; ++j) {
      int pe = s_pe[w][j], s = s_src[w][j], d = s_dst[w][j];
      if (d != cur_d) {
        size_t o = (size_t)cur_d * DIM + 2 * lane;
        atomicAdd(acc_h + o, am0);     atomicAdd(acc_h + o + 1, am1);
        atomicAdd(acc_s + o, as0);     atomicAdd(acc_s + o + 1, as1);
        am0 = am1 = as0 = as1 = 0.f;
        cur_d = d;
        ehp = *(const unsigned*)(Eh + (size_t)d * DIM + 2 * lane);
        eh0 = bf2f_lo(ehp); eh1 = bf2f_hi(ehp);
      }
      unsigned ce = *(const unsigned*)(Ce_enew + (size_t)pe * DIM + 2 * lane);
      unsigned dh = *(const unsigned*)(Dh + (size_t)s * DIM + 2 * lane);
      unsigned bh = *(const unsigned*)(Bh + (size_t)s * DIM + 2 * lane);
      float e0 = bf2f_lo(ce) + bf2f_lo(dh) + eh0;
      float e1 = bf2f_hi(ce) + bf2f_hi(dh) + eh1;
      *(unsigned*)(Ce_enew + (size_t)pe * DIM + 2 * lane) =
          (unsigned)f2bf(e0) | ((unsigned)f2bf(e1) << 16);
      sum0 += e0; q0 += e0 * e0;
      sum1 += e1; q1 += e1 * e1;
      float sg0 = 1.f / (1.f + __expf(-e0));
      float sg1 = 1.f / (1.f + __expf(-e1));
      am0 += bf2f_lo(bh) * sg0; am1 += bf2f_hi(bh) * sg1;
      as0 += sg0; as1 += sg1;
    }
    size_t o = (size_t)cur_d * DIM + 2 * lane;
    atomicAdd(acc_h + o, am0);     atomicAdd(acc_h + o + 1, am1);
    atomicAdd(acc_s + o, as0);     atomicAdd(acc_s + o + 1, as1);
  }
  atomicAdd(&s_sum[2 * lane], sum0);  atomicAdd(&s_sum[2 * lane + 1], sum1);
  atomicAdd(&s_sum2[2 * lane], q0);   atomicAdd(&s_sum2[2 * lane + 1], q1);
  __syncthreads();
  if (threadIdx.x < 128) {
    atomicAdd(stat_sum + threadIdx.x, s_sum[threadIdx.x]);
    atomicAdd(stat_sum2 + threadIdx.x, s_sum2[threadIdx.x]);
  }
}

// ---- K5: streaming BN apply on edges: e_out = e + relu(e_new*sc + sh) ----
__global__ __launch_bounds__(256) void bn_apply_e(
    const float* __restrict__ e, const unsigned short* __restrict__ enew,
    const float* __restrict__ scale, const float* __restrict__ shift,
    float* __restrict__ eout) {
  const size_t total8 = (size_t)N_EDGES * DIM / 8;
  for (size_t i = (size_t)blockIdx.x * blockDim.x + threadIdx.x; i < total8;
       i += (size_t)gridDim.x * blockDim.x) {
    int colbase = (int)((i * 8) & (DIM - 1));
    u32x4 en = ((const u32x4*)enew)[i];
    f32x4 e0 = ((const f32x4*)e)[2 * i];
    f32x4 e1 = ((const f32x4*)e)[2 * i + 1];
    f32x4 sc0 = *(const f32x4*)(scale + colbase);
    f32x4 sc1 = *(const f32x4*)(scale + colbase + 4);
    f32x4 sh0 = *(const f32x4*)(shift + colbase);
    f32x4 sh1 = *(const f32x4*)(shift + colbase + 4);
    f32x4 o0, o1;
#pragma unroll
    for (int j = 0; j < 4; ++j) {
      unsigned p = en[j >> 1];  // not used; keep simple below
    }
    // unpack 8 bf16
    float v[8];
#pragma unroll
    for (int j = 0; j < 4; ++j) {
      v[2 * j]     = bf2f_lo(en[j]);
      v[2 * j + 1] = bf2f_hi(en[j]);
    }
#pragma unroll
    for (int j = 0; j < 4; ++j) {
      float y0 = v[j] * sc0[j] + sh0[j];
      o0[j] = e0[j] + fmaxf(y0, 0.f);
      float y1 = v[4 + j] * sc1[j] + sh1[j];
      o1[j] = e1[j] + fmaxf(y1, 0.f);
    }
    ((f32x4*)eout)[2 * i] = o0;
    ((f32x4*)eout)[2 * i + 1] = o1;
  }
}

// ---- node_pre: h_new pre-activation + BN-h stats ----
__global__ __launch_bounds__(256) void node_pre(
    const float* __restrict__ Ah, const float* __restrict__ acc_h,
    const float* __restrict__ acc_s, float* __restrict__ pre_out,
    float* __restrict__ stat_sum, float* __restrict__ stat_sum2) {
  __shared__ float s_sum[128], s_sum2[128];
  if (threadIdx.x < 128) { s_sum[threadIdx.x] = 0.f; s_sum2[threadIdx.x] = 0.f; }
  __syncthreads();
  const int total4 = N_NODES * DIM / 4;
  float ls[4] = {0, 0, 0, 0}, lq[4] = {0, 0, 0, 0};
  int colbase = (threadIdx.x & 31) * 4;
  for (int i = blockIdx.x * blockDim.x + threadIdx.x; i < total4;
       i += gridDim.x * blockDim.x) {
    f32x4 a = ((const f32x4*)Ah)[i];
    f32x4 mh = ((const f32x4*)acc_h)[i];
    f32x4 ms = ((const f32x4*)acc_s)[i];
    f32x4 p;
#pragma unroll
    for (int j = 0; j < 4; ++j) {
      p[j] = a[j] + mh[j] / (ms[j] + 1e-6f);
      ls[j] += p[j]; lq[j] += p[j] * p[j];
    }
    ((f32x4*)pre_out)[i] = p;
  }
#pragma unroll
  for (int j = 0; j < 4; ++j) {
    atomicAdd(&s_sum[colbase + j], ls[j]);
    atomicAdd(&s_sum2[colbase + j], lq[j]);
  }
  __syncthreads();
  if (threadIdx.x < 128) {
    atomicAdd(stat_sum + threadIdx.x, s_sum[threadIdx.x]);
    atomicAdd(stat_sum2 + threadIdx.x, s_sum2[threadIdx.x]);
  }
}

__global__ void finalize_stats(const float* __restrict__ sum, const float* __restrict__ sum2,
                               const float* __restrict__ gamma, const float* __restrict__ beta,
                               float count, float* __restrict__ scale, float* __restrict__ shift) {
  int c = threadIdx.x;
  if (c < 128) {
    float mu = sum[c] / count;
    float var = sum2[c] / count - mu * mu;
    float inv = rsqrtf(var + 1e-5f);
    float sc = gamma[c] * inv;
    scale[c] = sc;
    shift[c] = beta[c] - mu * sc;
  }
}

__global__ __launch_bounds__(256) void node_final(
    const float* __restrict__ h, float* __restrict__ hout,
    const float* __restrict__ scale, const float* __restrict__ shift) {
  const int total4 = N_NODES * DIM / 4;
  for (int i = blockIdx.x * blockDim.x + threadIdx.x; i < total4;
       i += gridDim.x * blockDim.x) {
    f32x4 p = ((const f32x4*)hout)[i];
    f32x4 hv = ((const f32x4*)h)[i];
    f32x4 sc4 = ((const f32x4*)scale)[i & 31];
    f32x4 sh4 = ((const f32x4*)shift)[i & 31];
    f32x4 o;
#pragma unroll
    for (int j = 0; j < 4; ++j) {
      float y = p[j] * sc4[j] + sh4[j];
      o[j] = hv[j] + fmaxf(y, 0.f);
    }
    ((f32x4*)hout)[i] = o;
  }
}

extern "C" void kernel_launch(void* const* d_in, const int* in_sizes, int n_in,
                              void* d_out, int out_size, void* d_ws, size_t ws_size,
                              hipStream_t stream) {
  const float* h   = (const float*)d_in[0];
  const float* e   = (const float*)d_in[1];
  const int*   src = (const int*)d_in[2];
  const int*   dst = (const int*)d_in[3];
  const float* Aw = (const float*)d_in[4];  const float* Ab = (const float*)d_in[5];
  const float* Bw = (const float*)d_in[6];  const float* Bb = (const float*)d_in[7];
  const float* Cw = (const float*)d_in[8];  const float* Cb = (const float*)d_in[9];
  const float* Dw = (const float*)d_in[10]; const float* Db = (const float*)d_in[11];
  const float* Ew = (const float*)d_in[12]; const float* Eb = (const float*)d_in[13];
  const float* bn_h_g = (const float*)d_in[14]; const float* bn_h_b = (const float*)d_in[15];
  const float* bn_e_g = (const float*)d_in[16]; const float* bn_e_b = (const float*)d_in[17];

  const size_t ND_F32 = (size_t)N_NODES * DIM * 4;   // 25.6 MB
  const size_t ND_BF  = (size_t)N_NODES * DIM * 2;   // 12.8 MB
  const size_t ED_BF  = (size_t)N_EDGES * DIM * 2;   // 153.6 MB
  char* ws = (char*)d_ws;
  unsigned short* wbf = (unsigned short*)ws;          // 163840 B
  size_t off = 163840;
  float* Ah = (float*)(ws + off);           off += ND_F32;
  unsigned short* Bh = (unsigned short*)(ws + off); off += ND_BF;
  unsigned short* Dh = (unsigned short*)(ws + off); off += ND_BF;
  unsigned short* Eh = (unsigned short*)(ws + off); off += ND_BF;
  unsigned short* Ce = (unsigned short*)(ws + off); off += ED_BF;  // Ce -> e_new in place
  // ---- zeroed region ----
  char* zero_base = ws + off;
  float* acc_h = (float*)(ws + off); off += ND_F32;
  float* acc_s = (float*)(ws + off); off += ND_F32;
  int* counts  = (int*)(ws + off);   off += 200000;
  int* cursor  = (int*)(ws + off);   off += 200000;
  float* stats = (float*)(ws + off); off += 4096;
  size_t zero_bytes = (size_t)(ws + off - zero_base);
  // ---- not zeroed ----
  int* offsets = (int*)(ws + off);   off += 200064;
  int* perm    = (int*)(ws + off);   off += 2400000;

  float* e_sum = stats,        *e_sum2 = stats + 128;
  float* h_sum = stats + 256,  *h_sum2 = stats + 384;
  float* scale_e = stats + 512, *shift_e = stats + 640;
  float* scale_h = stats + 768, *shift_h = stats + 896;

  float* hout = (float*)d_out;
  float* eout = (float*)d_out + (size_t)N_NODES * DIM;

  hipMemsetAsync(zero_base, 0, zero_bytes, stream);

  convert_weights<<<320, 256, 0, stream>>>(Aw, Bw, Cw, Dw, Ew, wbf);
  hist_kernel<<<(N_EDGES + 255) / 256, 256, 0, stream>>>(dst, counts);
  scan_kernel<<<1, 1024, 0, stream>>>(counts, offsets);
  bucket_kernel<<<(N_EDGES + 255) / 256, 256, 0, stream>>>(dst, offsets, cursor, perm);
  node_gemm<<<(N_NODES + 63) / 64, 256, 0, stream>>>(h, wbf, Ab, Bb, Db, Eb, Ah, Bh, Dh, Eh);
  ce_gemm<<<2048, 256, 0, stream>>>(e, wbf, Cb, Ce);
  edge_gather<<<(N_TILES + 3) / 4, 256, 0, stream>>>(src, dst, perm, Bh, Dh, Eh, Ce,
      acc_h, acc_s, e_sum, e_sum2);
  finalize_stats<<<1, 128, 0, stream>>>(e_sum, e_sum2, bn_e_g, bn_e_b, (float)N_EDGES,
      scale_e, shift_e);
  node_pre<<<1024, 256, 0, stream>>>(Ah, acc_h, acc_s, hout, h_sum, h_sum2);
  finalize_stats<<<1, 128, 0, stream>>>(h_sum, h_sum2, bn_h_g, bn_h_b, (float)N_NODES,
      scale_h, shift_h);
  bn_apply_e<<<2048, 256, 0, stream>>>(e, Ce, scale_e, shift_e, eout);
  node_final<<<1024, 256, 0, stream>>>(h, hout, scale_h, shift_h);
}

// Round 4
// 725.660 us; speedup vs baseline: 1.6049x; 1.0458x over previous
//
#include <hip/hip_runtime.h>
#include <stdint.h>

#define N_NODES 50000
#define N_EDGES 600000
#define DIM 128
#define N_TILES (N_EDGES / 64)   // 9375
#define GATHER_BLOCKS 2048
#define GATHER_WAVES (GATHER_BLOCKS * 4)

typedef __attribute__((ext_vector_type(8))) short bf16x8;
typedef __attribute__((ext_vector_type(4))) float f32x4;
typedef __attribute__((ext_vector_type(4))) unsigned int u32x4;
typedef __attribute__((ext_vector_type(2))) unsigned int u32x2;

__device__ inline unsigned short f2bf(float f) {
  unsigned u = __builtin_bit_cast(unsigned, f);
  unsigned r = 0x7fffu + ((u >> 16) & 1u);
  return (unsigned short)((u + r) >> 16);
}
__device__ inline float bf2f_lo(unsigned p) { return __builtin_bit_cast(float, p << 16); }
__device__ inline float bf2f_hi(unsigned p) { return __builtin_bit_cast(float, p & 0xffff0000u); }

// ---- LDS staging (swizzled bf16 tiles, row stride 256 B) ----
__device__ inline void stage_pack_store(char* lds, int row, int f, f32x4 v0, f32x4 v1) {
  u32x4 q;
  q[0] = (unsigned)f2bf(v0[0]) | ((unsigned)f2bf(v0[1]) << 16);
  q[1] = (unsigned)f2bf(v0[2]) | ((unsigned)f2bf(v0[3]) << 16);
  q[2] = (unsigned)f2bf(v1[0]) | ((unsigned)f2bf(v1[1]) << 16);
  q[3] = (unsigned)f2bf(v1[2]) | ((unsigned)f2bf(v1[3]) << 16);
  int byte = (f * 16) ^ ((row & 7) << 4);
  *(u32x4*)(lds + row * 256 + byte) = q;
}

__device__ inline void stage_tile_f32(const float* __restrict__ src, int row0,
                                      int nvalid, char* lds) {
#pragma unroll
  for (int it = 0; it < 4; ++it) {
    int c = it * 256 + threadIdx.x;
    int row = c >> 4, f = c & 15;
    f32x4 v0 = {0, 0, 0, 0}, v1 = {0, 0, 0, 0};
    if (row < nvalid) {
      const f32x4* p = (const f32x4*)(src + (size_t)(row0 + row) * DIM + f * 8);
      v0 = p[0]; v1 = p[1];
    }
    stage_pack_store(lds, row, f, v0, v1);
  }
}

__device__ inline void stage_w(const unsigned short* __restrict__ wbf, char* lds) {
#pragma unroll
  for (int it = 0; it < 8; ++it) {
    int c = it * 256 + threadIdx.x;
    int row = c >> 4, f = c & 15;
    u32x4 q = *(const u32x4*)(wbf + row * 128 + f * 8);
    int byte = (f * 16) ^ ((row & 7) << 4);
    *(u32x4*)(lds + row * 256 + byte) = q;
  }
}

__device__ inline bf16x8 read_frag(const char* lds, int row, int ks, int lane) {
  int byte = ks * 64 + ((lane >> 4) * 16);
  byte ^= ((row & 7) << 4);
  return *(const bf16x8*)(lds + row * 256 + byte);
}

// ---- K0: fp32 -> bf16 weights ----
__global__ void convert_weights(const float* __restrict__ a, const float* __restrict__ b,
                                const float* __restrict__ c, const float* __restrict__ d,
                                const float* __restrict__ e5, unsigned short* __restrict__ out) {
  int i = blockIdx.x * 256 + threadIdx.x;
  if (i >= 5 * 16384) return;
  int m = i >> 14, k = i & 16383;
  const float* p = (m == 0) ? a : (m == 1) ? b : (m == 2) ? c : (m == 3) ? d : e5;
  out[i] = f2bf(p[k]);
}

// ---- CSR build ----
__global__ void hist_kernel(const int* __restrict__ dst, int* __restrict__ counts) {
  int i = blockIdx.x * 256 + threadIdx.x;
  if (i < N_EDGES) atomicAdd(&counts[dst[i]], 1);
}

__global__ __launch_bounds__(1024) void scan_kernel(const int* __restrict__ counts,
                                                    int* __restrict__ offsets) {
  __shared__ int part[1024];
  const int CHK = 49;
  int t = threadIdx.x;
  int base = t * CHK;
  int s = 0;
  for (int k = 0; k < CHK; ++k) {
    int i = base + k;
    if (i < N_NODES) s += counts[i];
  }
  part[t] = s;
  __syncthreads();
  for (int off = 1; off < 1024; off <<= 1) {
    int v = part[t];
    int u = (t >= off) ? part[t - off] : 0;
    __syncthreads();
    part[t] = v + u;
    __syncthreads();
  }
  int run = (t == 0) ? 0 : part[t - 1];
  for (int k = 0; k < CHK; ++k) {
    int i = base + k;
    if (i < N_NODES) { offsets[i] = run; run += counts[i]; }
  }
  if (t == 1023) offsets[N_NODES] = run;
}

__global__ void bucket_kernel(const int* __restrict__ dst, const int* __restrict__ offsets,
                              int* __restrict__ cursor, int* __restrict__ perm) {
  int i = blockIdx.x * 256 + threadIdx.x;
  if (i < N_EDGES) {
    int d = dst[i];
    int p = offsets[d] + atomicAdd(&cursor[d], 1);
    perm[p] = i;
  }
}

// ---- K1: node GEMMs. Ah fp32; DB interleaved (D|B per lane-pair) bf16; Eh bf16 ----
// DB layout: row r (256 ushort): [4*(c>>1) + (c&1)] = Dh[r][c], [4*(c>>1)+2+(c&1)] = Bh[r][c]
__global__ __launch_bounds__(256) void node_gemm(
    const float* __restrict__ h, const unsigned short* __restrict__ wbf,
    const float* __restrict__ Ab, const float* __restrict__ Bb,
    const float* __restrict__ Db, const float* __restrict__ Eb,
    float* __restrict__ Ah, unsigned short* __restrict__ DB,
    unsigned short* __restrict__ Eh) {
  __shared__ __align__(16) char lds_x[64 * 256];
  __shared__ __align__(16) char lds_w[128 * 256];
  int tile = blockIdx.x * 64;
  int nvalid = N_NODES - tile; if (nvalid > 64) nvalid = 64;
  stage_tile_f32(h, tile, nvalid, lds_x);
  int lane = threadIdx.x & 63, w = threadIdx.x >> 6;
  int prow = w * 16 + (lane & 15);
  __syncthreads();
  bf16x8 a[4];
#pragma unroll
  for (int ks = 0; ks < 4; ++ks) a[ks] = read_frag(lds_x, prow, ks, lane);

  const int wmat[4] = {0, 1, 3, 4};           // A,B,D,E
  const float* const biases[4] = {Ab, Bb, Db, Eb};
#pragma unroll
  for (int m = 0; m < 4; ++m) {
    __syncthreads();
    stage_w(wbf + wmat[m] * 16384, lds_w);
    __syncthreads();
    f32x4 acc[8] = {};
#pragma unroll
    for (int ct = 0; ct < 8; ++ct) {
#pragma unroll
      for (int ks = 0; ks < 4; ++ks) {
        bf16x8 b = read_frag(lds_w, ct * 16 + (lane & 15), ks, lane);
        acc[ct] = __builtin_amdgcn_mfma_f32_16x16x32_bf16(a[ks], b, acc[ct], 0, 0, 0);
      }
    }
    const float* bias = biases[m];
#pragma unroll
    for (int ct = 0; ct < 8; ++ct) {
      int col = ct * 16 + (lane & 15);
      float bv = bias[col];
#pragma unroll
      for (int j = 0; j < 4; ++j) {
        int r = tile + w * 16 + (lane >> 4) * 4 + j;
        if (r < N_NODES) {
          float v = acc[ct][j] + bv;
          if (m == 0) Ah[(size_t)r * DIM + col] = v;
          else if (m == 1) DB[(size_t)r * 256 + 4 * (col >> 1) + 2 + (col & 1)] = f2bf(v);
          else if (m == 2) DB[(size_t)r * 256 + 4 * (col >> 1) + (col & 1)] = f2bf(v);
          else Eh[(size_t)r * DIM + col] = f2bf(v);
        }
      }
    }
  }
}

// ---- K2: Ce = e @ C^T + Cb -> bf16 ----
__global__ __launch_bounds__(256) void ce_gemm(
    const float* __restrict__ e, const unsigned short* __restrict__ wbf,
    const float* __restrict__ Cb, unsigned short* __restrict__ Ce) {
  __shared__ __align__(16) char lds_x[64 * 256];
  __shared__ __align__(16) char lds_w[128 * 256];
  stage_w(wbf + 2 * 16384, lds_w);
  int lane = threadIdx.x & 63, w = threadIdx.x >> 6;
  int prow = w * 16 + (lane & 15);
  for (int tile = blockIdx.x; tile < N_TILES; tile += gridDim.x) {
    __syncthreads();
    stage_tile_f32(e, tile * 64, 64, lds_x);
    __syncthreads();
    bf16x8 a[4];
#pragma unroll
    for (int ks = 0; ks < 4; ++ks) a[ks] = read_frag(lds_x, prow, ks, lane);
    f32x4 acc[8] = {};
#pragma unroll
    for (int ct = 0; ct < 8; ++ct) {
#pragma unroll
      for (int ks = 0; ks < 4; ++ks) {
        bf16x8 b = read_frag(lds_w, ct * 16 + (lane & 15), ks, lane);
        acc[ct] = __builtin_amdgcn_mfma_f32_16x16x32_bf16(a[ks], b, acc[ct], 0, 0, 0);
      }
    }
#pragma unroll
    for (int ct = 0; ct < 8; ++ct) {
      int col = ct * 16 + (lane & 15);
      float bv = Cb[col];
#pragma unroll
      for (int j = 0; j < 4; ++j) {
        int r = tile * 64 + w * 16 + (lane >> 4) * 4 + j;
        Ce[(size_t)r * DIM + col] = f2bf(acc[ct][j] + bv);
      }
    }
  }
}

// ---- K3: gather/scatter over dst-sorted edges. Balanced per-wave ranges,
//      double-buffered 3-edge chunks for deep MLP. ----
__global__ __launch_bounds__(256) void edge_gather(
    const int* __restrict__ src, const int* __restrict__ dst, const int* __restrict__ perm,
    const unsigned short* __restrict__ DB, const unsigned short* __restrict__ Eh,
    unsigned short* __restrict__ Ce_enew,
    float* __restrict__ acc_h, float* __restrict__ acc_s,
    float* __restrict__ stat_sum, float* __restrict__ stat_sum2) {
  __shared__ int s_pe[4][80], s_src[4][80], s_dst[4][80];
  __shared__ float s_sum[128], s_sum2[128];
  if (threadIdx.x < 128) { s_sum[threadIdx.x] = 0.f; s_sum2[threadIdx.x] = 0.f; }
  int w = threadIdx.x >> 6, lane = threadIdx.x & 63;
  long long wid = (long long)blockIdx.x * 4 + w;
  int base = (int)((wid * N_EDGES) / GATHER_WAVES);
  int end  = (int)(((wid + 1) * N_EDGES) / GATHER_WAVES);
  int n = end - base;                          // 73 or 74
  for (int j = lane; j < n; j += 64) {
    int pe = perm[base + j];
    s_pe[w][j] = pe;
    s_src[w][j] = src[pe];
    s_dst[w][j] = dst[pe];
  }
  __syncthreads();

  float sum0 = 0.f, sum1 = 0.f, q0 = 0.f, q1 = 0.f;
  float am0 = 0.f, am1 = 0.f, as0 = 0.f, as1 = 0.f;
  int cur_d = s_dst[w][0];

  const int CH = 3;
  unsigned ceA[CH], ehA[CH]; u32x2 dbA[CH];
  unsigned ceB[CH], ehB[CH]; u32x2 dbB[CH];

  auto issue1 = [&](int j, unsigned& ce, u32x2& db, unsigned& eh) {
    int pe = s_pe[w][j], s = s_src[w][j], d = s_dst[w][j];
    ce = *(const unsigned*)(Ce_enew + (size_t)pe * DIM + 2 * lane);
    db = *(const u32x2*)(DB + (size_t)s * 256 + 4 * lane);
    eh = *(const unsigned*)(Eh + (size_t)d * DIM + 2 * lane);
  };
  auto proc1 = [&](int j, unsigned ce, u32x2 db, unsigned eh) {
    int pe = s_pe[w][j], d = s_dst[w][j];
    if (d != cur_d) {                           // wave-uniform branch
      size_t o = (size_t)cur_d * DIM + 2 * lane;
      atomicAdd(acc_h + o, am0); atomicAdd(acc_h + o + 1, am1);
      atomicAdd(acc_s + o, as0); atomicAdd(acc_s + o + 1, as1);
      am0 = am1 = as0 = as1 = 0.f;
      cur_d = d;
    }
    float e0 = bf2f_lo(ce) + bf2f_lo(db[0]) + bf2f_lo(eh);
    float e1 = bf2f_hi(ce) + bf2f_hi(db[0]) + bf2f_hi(eh);
    *(unsigned*)(Ce_enew + (size_t)pe * DIM + 2 * lane) =
        (unsigned)f2bf(e0) | ((unsigned)f2bf(e1) << 16);
    sum0 += e0; q0 += e0 * e0;
    sum1 += e1; q1 += e1 * e1;
    float sg0 = 1.f / (1.f + __expf(-e0));
    float sg1 = 1.f / (1.f + __expf(-e1));
    am0 += bf2f_lo(db[1]) * sg0; am1 += bf2f_hi(db[1]) * sg1;
    as0 += sg0; as1 += sg1;
  };

  int nA = n < CH ? n : CH;
#pragma unroll
  for (int k = 0; k < CH; ++k) if (k < nA) issue1(k, ceA[k], dbA[k], ehA[k]);
  for (int jb = 0; jb < n; jb += 2 * CH) {
    int bbase = jb + CH;
    int cntB = n - bbase; cntB = cntB < 0 ? 0 : (cntB > CH ? CH : cntB);
#pragma unroll
    for (int k = 0; k < CH; ++k) if (k < cntB) issue1(bbase + k, ceB[k], dbB[k], ehB[k]);
    int cntA = n - jb; cntA = cntA > CH ? CH : cntA;
#pragma unroll
    for (int k = 0; k < CH; ++k) if (k < cntA) proc1(jb + k, ceA[k], dbA[k], ehA[k]);
    int abase = jb + 2 * CH;
    int cntA2 = n - abase; cntA2 = cntA2 < 0 ? 0 : (cntA2 > CH ? CH : cntA2);
#pragma unroll
    for (int k = 0; k < CH; ++k) if (k < cntA2) issue1(abase + k, ceA[k], dbA[k], ehA[k]);
#pragma unroll
    for (int k = 0; k < CH; ++k) if (k < cntB) proc1(bbase + k, ceB[k], dbB[k], ehB[k]);
  }
  size_t o = (size_t)cur_d * DIM + 2 * lane;
  atomicAdd(acc_h + o, am0); atomicAdd(acc_h + o + 1, am1);
  atomicAdd(acc_s + o, as0); atomicAdd(acc_s + o + 1, as1);

  atomicAdd(&s_sum[2 * lane], sum0);  atomicAdd(&s_sum[2 * lane + 1], sum1);
  atomicAdd(&s_sum2[2 * lane], q0);   atomicAdd(&s_sum2[2 * lane + 1], q1);
  __syncthreads();
  if (threadIdx.x < 128) {
    atomicAdd(stat_sum + threadIdx.x, s_sum[threadIdx.x]);
    atomicAdd(stat_sum2 + threadIdx.x, s_sum2[threadIdx.x]);
  }
}

// ---- K5: streaming BN apply on edges ----
__global__ __launch_bounds__(256) void bn_apply_e(
    const float* __restrict__ e, const unsigned short* __restrict__ enew,
    const float* __restrict__ scale, const float* __restrict__ shift,
    float* __restrict__ eout) {
  const size_t total8 = (size_t)N_EDGES * DIM / 8;
  for (size_t i = (size_t)blockIdx.x * blockDim.x + threadIdx.x; i < total8;
       i += (size_t)gridDim.x * blockDim.x) {
    int colbase = (int)((i * 8) & (DIM - 1));
    u32x4 en = ((const u32x4*)enew)[i];
    f32x4 e0 = ((const f32x4*)e)[2 * i];
    f32x4 e1 = ((const f32x4*)e)[2 * i + 1];
    f32x4 sc0 = *(const f32x4*)(scale + colbase);
    f32x4 sc1 = *(const f32x4*)(scale + colbase + 4);
    f32x4 sh0 = *(const f32x4*)(shift + colbase);
    f32x4 sh1 = *(const f32x4*)(shift + colbase + 4);
    float v[8];
#pragma unroll
    for (int j = 0; j < 4; ++j) {
      v[2 * j]     = bf2f_lo(en[j]);
      v[2 * j + 1] = bf2f_hi(en[j]);
    }
    f32x4 o0, o1;
#pragma unroll
    for (int j = 0; j < 4; ++j) {
      float y0 = v[j] * sc0[j] + sh0[j];
      o0[j] = e0[j] + fmaxf(y0, 0.f);
      float y1 = v[4 + j] * sc1[j] + sh1[j];
      o1[j] = e1[j] + fmaxf(y1, 0.f);
    }
    ((f32x4*)eout)[2 * i] = o0;
    ((f32x4*)eout)[2 * i + 1] = o1;
  }
}

// ---- node_pre: h_new pre-activation + BN-h stats ----
__global__ __launch_bounds__(256) void node_pre(
    const float* __restrict__ Ah, const float* __restrict__ acc_h,
    const float* __restrict__ acc_s, float* __restrict__ pre_out,
    float* __restrict__ stat_sum, float* __restrict__ stat_sum2) {
  __shared__ float s_sum[128], s_sum2[128];
  if (threadIdx.x < 128) { s_sum[threadIdx.x] = 0.f; s_sum2[threadIdx.x] = 0.f; }
  __syncthreads();
  const int total4 = N_NODES * DIM / 4;
  float ls[4] = {0, 0, 0, 0}, lq[4] = {0, 0, 0, 0};
  int colbase = (threadIdx.x & 31) * 4;
  for (int i = blockIdx.x * blockDim.x + threadIdx.x; i < total4;
       i += gridDim.x * blockDim.x) {
    f32x4 a = ((const f32x4*)Ah)[i];
    f32x4 mh = ((const f32x4*)acc_h)[i];
    f32x4 ms = ((const f32x4*)acc_s)[i];
    f32x4 p;
#pragma unroll
    for (int j = 0; j < 4; ++j) {
      p[j] = a[j] + mh[j] / (ms[j] + 1e-6f);
      ls[j] += p[j]; lq[j] += p[j] * p[j];
    }
    ((f32x4*)pre_out)[i] = p;
  }
#pragma unroll
  for (int j = 0; j < 4; ++j) {
    atomicAdd(&s_sum[colbase + j], ls[j]);
    atomicAdd(&s_sum2[colbase + j], lq[j]);
  }
  __syncthreads();
  if (threadIdx.x < 128) {
    atomicAdd(stat_sum + threadIdx.x, s_sum[threadIdx.x]);
    atomicAdd(stat_sum2 + threadIdx.x, s_sum2[threadIdx.x]);
  }
}

__global__ void finalize_stats(const float* __restrict__ sum, const float* __restrict__ sum2,
                               const float* __restrict__ gamma, const float* __restrict__ beta,
                               float count, float* __restrict__ scale, float* __restrict__ shift) {
  int c = threadIdx.x;
  if (c < 128) {
    float mu = sum[c] / count;
    float var = sum2[c] / count - mu * mu;
    float inv = rsqrtf(var + 1e-5f);
    float sc = gamma[c] * inv;
    scale[c] = sc;
    shift[c] = beta[c] - mu * sc;
  }
}

__global__ __launch_bounds__(256) void node_final(
    const float* __restrict__ h, float* __restrict__ hout,
    const float* __restrict__ scale, const float* __restrict__ shift) {
  const int total4 = N_NODES * DIM / 4;
  for (int i = blockIdx.x * blockDim.x + threadIdx.x; i < total4;
       i += gridDim.x * blockDim.x) {
    f32x4 p = ((const f32x4*)hout)[i];
    f32x4 hv = ((const f32x4*)h)[i];
    f32x4 sc4 = ((const f32x4*)scale)[i & 31];
    f32x4 sh4 = ((const f32x4*)shift)[i & 31];
    f32x4 o;
#pragma unroll
    for (int j = 0; j < 4; ++j) {
      float y = p[j] * sc4[j] + sh4[j];
      o[j] = hv[j] + fmaxf(y, 0.f);
    }
    ((f32x4*)hout)[i] = o;
  }
}

extern "C" void kernel_launch(void* const* d_in, const int* in_sizes, int n_in,
                              void* d_out, int out_size, void* d_ws, size_t ws_size,
                              hipStream_t stream) {
  const float* h   = (const float*)d_in[0];
  const float* e   = (const float*)d_in[1];
  const int*   src = (const int*)d_in[2];
  const int*   dst = (const int*)d_in[3];
  const float* Aw = (const float*)d_in[4];  const float* Ab = (const float*)d_in[5];
  const float* Bw = (const float*)d_in[6];  const float* Bb = (const float*)d_in[7];
  const float* Cw = (const float*)d_in[8];  const float* Cb = (const float*)d_in[9];
  const float* Dw = (const float*)d_in[10]; const float* Db = (const float*)d_in[11];
  const float* Ew = (const float*)d_in[12]; const float* Eb = (const float*)d_in[13];
  const float* bn_h_g = (const float*)d_in[14]; const float* bn_h_b = (const float*)d_in[15];
  const float* bn_e_g = (const float*)d_in[16]; const float* bn_e_b = (const float*)d_in[17];

  const size_t ND_F32 = (size_t)N_NODES * DIM * 4;   // 25.6 MB
  const size_t ND_BF  = (size_t)N_NODES * DIM * 2;   // 12.8 MB
  const size_t ED_BF  = (size_t)N_EDGES * DIM * 2;   // 153.6 MB
  char* ws = (char*)d_ws;
  unsigned short* wbf = (unsigned short*)ws;          // 163840 B
  size_t off = 163840;
  float* Ah = (float*)(ws + off);                   off += ND_F32;
  unsigned short* DB = (unsigned short*)(ws + off); off += 2 * ND_BF;  // interleaved D|B
  unsigned short* Eh = (unsigned short*)(ws + off); off += ND_BF;
  unsigned short* Ce = (unsigned short*)(ws + off); off += ED_BF;  // Ce -> e_new in place
  // ---- zeroed region ----
  char* zero_base = ws + off;
  float* acc_h = (float*)(ws + off); off += ND_F32;
  float* acc_s = (float*)(ws + off); off += ND_F32;
  int* counts  = (int*)(ws + off);   off += 200000;
  int* cursor  = (int*)(ws + off);   off += 200000;
  float* stats = (float*)(ws + off); off += 4096;
  size_t zero_bytes = (size_t)(ws + off - zero_base);
  // ---- not zeroed ----
  int* offsets = (int*)(ws + off);   off += 200064;
  int* perm    = (int*)(ws + off);   off += 2400000;

  float* e_sum = stats,        *e_sum2 = stats + 128;
  float* h_sum = stats + 256,  *h_sum2 = stats + 384;
  float* scale_e = stats + 512, *shift_e = stats + 640;
  float* scale_h = stats + 768, *shift_h = stats + 896;

  float* hout = (float*)d_out;
  float* eout = (float*)d_out + (size_t)N_NODES * DIM;

  hipMemsetAsync(zero_base, 0, zero_bytes, stream);

  convert_weights<<<320, 256, 0, stream>>>(Aw, Bw, Cw, Dw, Ew, wbf);
  hist_kernel<<<(N_EDGES + 255) / 256, 256, 0, stream>>>(dst, counts);
  scan_kernel<<<1, 1024, 0, stream>>>(counts, offsets);
  bucket_kernel<<<(N_EDGES + 255) / 256, 256, 0, stream>>>(dst, offsets, cursor, perm);
  node_gemm<<<(N_NODES + 63) / 64, 256, 0, stream>>>(h, wbf, Ab, Bb, Db, Eb, Ah, DB, Eh);
  ce_gemm<<<2048, 256, 0, stream>>>(e, wbf, Cb, Ce);
  edge_gather<<<GATHER_BLOCKS, 256, 0, stream>>>(src, dst, perm, DB, Eh, Ce,
      acc_h, acc_s, e_sum, e_sum2);
  finalize_stats<<<1, 128, 0, stream>>>(e_sum, e_sum2, bn_e_g, bn_e_b, (float)N_EDGES,
      scale_e, shift_e);
  node_pre<<<1024, 256, 0, stream>>>(Ah, acc_h, acc_s, hout, h_sum, h_sum2);
  finalize_stats<<<1, 128, 0, stream>>>(h_sum, h_sum2, bn_h_g, bn_h_b, (float)N_NODES,
      scale_h, shift_h);
  bn_apply_e<<<2048, 256, 0, stream>>>(e, Ce, scale_e, shift_e, eout);
  node_final<<<1024, 256, 0, stream>>>(h, hout, scale_h, shift_h);
}

// Round 5
// 724.701 us; speedup vs baseline: 1.6070x; 1.0013x over previous
//
#include <hip/hip_runtime.h>
#include <stdint.h>

#define N_NODES 50000
#define N_EDGES 600000
#define DIM 128
#define N_TILES (N_EDGES / 64)   // 9375
#define CE_BLOCKS 1875           // 9375 / 5 tiles each, exact
#define GATHER_BLOCKS 2048       // 8192 waves = 2^13

typedef __attribute__((ext_vector_type(8))) short bf16x8;
typedef __attribute__((ext_vector_type(4))) float f32x4;
typedef __attribute__((ext_vector_type(4))) unsigned int u32x4;
typedef __attribute__((ext_vector_type(2))) unsigned int u32x2;

__device__ inline unsigned short f2bf(float f) {
  unsigned u = __builtin_bit_cast(unsigned, f);
  unsigned r = 0x7fffu + ((u >> 16) & 1u);
  return (unsigned short)((u + r) >> 16);
}
__device__ inline float bf2f_lo(unsigned p) { return __builtin_bit_cast(float, p << 16); }
__device__ inline float bf2f_hi(unsigned p) { return __builtin_bit_cast(float, p & 0xffff0000u); }

// ---- LDS staging (swizzled bf16 tiles, row stride 256 B) ----
__device__ inline void stage_pack_store(char* lds, int row, int f, f32x4 v0, f32x4 v1) {
  u32x4 q;
  q[0] = (unsigned)f2bf(v0[0]) | ((unsigned)f2bf(v0[1]) << 16);
  q[1] = (unsigned)f2bf(v0[2]) | ((unsigned)f2bf(v0[3]) << 16);
  q[2] = (unsigned)f2bf(v1[0]) | ((unsigned)f2bf(v1[1]) << 16);
  q[3] = (unsigned)f2bf(v1[2]) | ((unsigned)f2bf(v1[3]) << 16);
  int byte = (f * 16) ^ ((row & 7) << 4);
  *(u32x4*)(lds + row * 256 + byte) = q;
}

__device__ inline void stage_tile_f32(const float* __restrict__ src, int row0,
                                      int nvalid, char* lds) {
#pragma unroll
  for (int it = 0; it < 4; ++it) {
    int c = it * 256 + threadIdx.x;
    int row = c >> 4, f = c & 15;
    f32x4 v0 = {0, 0, 0, 0}, v1 = {0, 0, 0, 0};
    if (row < nvalid) {
      const f32x4* p = (const f32x4*)(src + (size_t)(row0 + row) * DIM + f * 8);
      v0 = p[0]; v1 = p[1];
    }
    stage_pack_store(lds, row, f, v0, v1);
  }
}

__device__ inline void stage_w(const unsigned short* __restrict__ wbf, char* lds) {
#pragma unroll
  for (int it = 0; it < 8; ++it) {
    int c = it * 256 + threadIdx.x;
    int row = c >> 4, f = c & 15;
    u32x4 q = *(const u32x4*)(wbf + row * 128 + f * 8);
    int byte = (f * 16) ^ ((row & 7) << 4);
    *(u32x4*)(lds + row * 256 + byte) = q;
  }
}

__device__ inline bf16x8 read_frag(const char* lds, int row, int ks, int lane) {
  int byte = ks * 64 + ((lane >> 4) * 16);
  byte ^= ((row & 7) << 4);
  return *(const bf16x8*)(lds + row * 256 + byte);
}

// ---- K0: weight conversion + dst histogram (merged) ----
__global__ void setup_kernel(const float* __restrict__ a, const float* __restrict__ b,
                             const float* __restrict__ c, const float* __restrict__ d,
                             const float* __restrict__ e5, unsigned short* __restrict__ out,
                             const int* __restrict__ dst, int* __restrict__ counts) {
  int i = blockIdx.x * 256 + threadIdx.x;
  if (i < 5 * 16384) {
    int m = i >> 14, k = i & 16383;
    const float* p = (m == 0) ? a : (m == 1) ? b : (m == 2) ? c : (m == 3) ? d : e5;
    out[i] = f2bf(p[k]);
  }
  if (i < N_EDGES) atomicAdd(&counts[dst[i]], 1);
}

__global__ __launch_bounds__(1024) void scan_kernel(const int* __restrict__ counts,
                                                    int* __restrict__ offsets) {
  __shared__ int part[1024];
  const int CHK = 49;
  int t = threadIdx.x;
  int base = t * CHK;
  int s = 0;
  for (int k = 0; k < CHK; ++k) {
    int i = base + k;
    if (i < N_NODES) s += counts[i];
  }
  part[t] = s;
  __syncthreads();
  for (int off = 1; off < 1024; off <<= 1) {
    int v = part[t];
    int u = (t >= off) ? part[t - off] : 0;
    __syncthreads();
    part[t] = v + u;
    __syncthreads();
  }
  int run = (t == 0) ? 0 : part[t - 1];
  for (int k = 0; k < CHK; ++k) {
    int i = base + k;
    if (i < N_NODES) { offsets[i] = run; run += counts[i]; }
  }
  if (t == 1023) offsets[N_NODES] = run;
}

// meta[p] = (edge, src, dst, 0) in dst-sorted order
__global__ void bucket_kernel(const int* __restrict__ src, const int* __restrict__ dst,
                              const int* __restrict__ offsets, int* __restrict__ cursor,
                              int4* __restrict__ meta) {
  int i = blockIdx.x * 256 + threadIdx.x;
  if (i < N_EDGES) {
    int d = dst[i];
    int p = offsets[d] + atomicAdd(&cursor[d], 1);
    meta[p] = make_int4(i, src[i], d, 0);
  }
}

// ---- K1: node GEMMs. Ah fp32; DB interleaved (D|B per lane-pair) bf16; Eh bf16 ----
__global__ __launch_bounds__(256) void node_gemm(
    const float* __restrict__ h, const unsigned short* __restrict__ wbf,
    const float* __restrict__ Ab, const float* __restrict__ Bb,
    const float* __restrict__ Db, const float* __restrict__ Eb,
    float* __restrict__ Ah, unsigned short* __restrict__ DB,
    unsigned short* __restrict__ Eh) {
  __shared__ __align__(16) char lds_x[64 * 256];
  __shared__ __align__(16) char lds_w[128 * 256];
  int tile = blockIdx.x * 64;
  int nvalid = N_NODES - tile; if (nvalid > 64) nvalid = 64;
  stage_tile_f32(h, tile, nvalid, lds_x);
  int lane = threadIdx.x & 63, w = threadIdx.x >> 6;
  int prow = w * 16 + (lane & 15);
  __syncthreads();
  bf16x8 a[4];
#pragma unroll
  for (int ks = 0; ks < 4; ++ks) a[ks] = read_frag(lds_x, prow, ks, lane);

  const int wmat[4] = {0, 1, 3, 4};           // A,B,D,E
  const float* const biases[4] = {Ab, Bb, Db, Eb};
#pragma unroll
  for (int m = 0; m < 4; ++m) {
    __syncthreads();
    stage_w(wbf + wmat[m] * 16384, lds_w);
    __syncthreads();
    f32x4 acc[8] = {};
#pragma unroll
    for (int ct = 0; ct < 8; ++ct) {
#pragma unroll
      for (int ks = 0; ks < 4; ++ks) {
        bf16x8 b = read_frag(lds_w, ct * 16 + (lane & 15), ks, lane);
        acc[ct] = __builtin_amdgcn_mfma_f32_16x16x32_bf16(a[ks], b, acc[ct], 0, 0, 0);
      }
    }
    const float* bias = biases[m];
#pragma unroll
    for (int ct = 0; ct < 8; ++ct) {
      int col = ct * 16 + (lane & 15);
      float bv = bias[col];
#pragma unroll
      for (int j = 0; j < 4; ++j) {
        int r = tile + w * 16 + (lane >> 4) * 4 + j;
        if (r < N_NODES) {
          float v = acc[ct][j] + bv;
          if (m == 0) Ah[(size_t)r * DIM + col] = v;
          else if (m == 1) DB[(size_t)r * 256 + 4 * (col >> 1) + 2 + (col & 1)] = f2bf(v);
          else if (m == 2) DB[(size_t)r * 256 + 4 * (col >> 1) + (col & 1)] = f2bf(v);
          else Eh[(size_t)r * DIM + col] = f2bf(v);
        }
      }
    }
  }
}

// ---- K2: Ce = e @ C^T + Cb -> bf16 (5 tiles per block, exact) ----
__global__ __launch_bounds__(256) void ce_gemm(
    const float* __restrict__ e, const unsigned short* __restrict__ wbf,
    const float* __restrict__ Cb, unsigned short* __restrict__ Ce) {
  __shared__ __align__(16) char lds_x[64 * 256];
  __shared__ __align__(16) char lds_w[128 * 256];
  stage_w(wbf + 2 * 16384, lds_w);
  int lane = threadIdx.x & 63, w = threadIdx.x >> 6;
  int prow = w * 16 + (lane & 15);
  for (int tile = blockIdx.x; tile < N_TILES; tile += CE_BLOCKS) {
    __syncthreads();
    stage_tile_f32(e, tile * 64, 64, lds_x);
    __syncthreads();
    bf16x8 a[4];
#pragma unroll
    for (int ks = 0; ks < 4; ++ks) a[ks] = read_frag(lds_x, prow, ks, lane);
    f32x4 acc[8] = {};
#pragma unroll
    for (int ct = 0; ct < 8; ++ct) {
#pragma unroll
      for (int ks = 0; ks < 4; ++ks) {
        bf16x8 b = read_frag(lds_w, ct * 16 + (lane & 15), ks, lane);
        acc[ct] = __builtin_amdgcn_mfma_f32_16x16x32_bf16(a[ks], b, acc[ct], 0, 0, 0);
      }
    }
#pragma unroll
    for (int ct = 0; ct < 8; ++ct) {
      int col = ct * 16 + (lane & 15);
      float bv = Cb[col];
#pragma unroll
      for (int j = 0; j < 4; ++j) {
        int r = tile * 64 + w * 16 + (lane >> 4) * 4 + j;
        Ce[(size_t)r * DIM + col] = f2bf(acc[ct][j] + bv);
      }
    }
  }
}

// ---- K3: gather/scatter over dst-sorted edges.
// Scalar (SGPR) meta via s_load; wave-uniform row bases; separate enew output
// buffer so issue-loads pipeline past proc-stores. ----
__global__ __launch_bounds__(256, 8) void edge_gather(
    const int4* __restrict__ meta,
    const unsigned short* __restrict__ DB, const unsigned short* __restrict__ Eh,
    const unsigned short* __restrict__ Ce, unsigned short* __restrict__ enew,
    float* __restrict__ acc_h, float* __restrict__ acc_s,
    float* __restrict__ stat_sum, float* __restrict__ stat_sum2) {
  __shared__ float s_sum[128], s_sum2[128];
  if (threadIdx.x < 128) { s_sum[threadIdx.x] = 0.f; s_sum2[threadIdx.x] = 0.f; }
  __syncthreads();
  int lane = threadIdx.x & 63;
  int w = __builtin_amdgcn_readfirstlane(threadIdx.x >> 6);
  int wid = blockIdx.x * 4 + w;
  int base = (int)(((long long)wid * N_EDGES) >> 13);       // /8192 waves
  int end  = (int)(((long long)(wid + 1) * N_EDGES) >> 13);
  int n = end - base;                                       // 73 or 74
  const int4* mp = meta + base;

  float sum0 = 0.f, sum1 = 0.f, q0 = 0.f, q1 = 0.f;
  float am0 = 0.f, am1 = 0.f, as0 = 0.f, as1 = 0.f;
  int cur_d = mp[0].z;

  auto issue = [&](const int4& m, unsigned& ce, u32x2& db, unsigned& eh) {
    ce = *(const unsigned*)(Ce + (size_t)m.x * DIM + 2 * lane);
    db = *(const u32x2*)(DB + (size_t)m.y * 256 + 4 * lane);
    eh = *(const unsigned*)(Eh + (size_t)m.z * DIM + 2 * lane);
  };
  auto flush = [&]() {
    size_t o = (size_t)cur_d * DIM + 2 * lane;
    atomicAdd(acc_h + o, am0); atomicAdd(acc_h + o + 1, am1);
    atomicAdd(acc_s + o, as0); atomicAdd(acc_s + o + 1, as1);
    am0 = am1 = as0 = as1 = 0.f;
  };
  auto proc = [&](int pe, int d, unsigned ce, u32x2 db, unsigned eh) {
    if (d != cur_d) { flush(); cur_d = d; }
    float e0 = bf2f_lo(ce) + bf2f_lo(db[0]) + bf2f_lo(eh);
    float e1 = bf2f_hi(ce) + bf2f_hi(db[0]) + bf2f_hi(eh);
    *(unsigned*)(enew + (size_t)pe * DIM + 2 * lane) =
        (unsigned)f2bf(e0) | ((unsigned)f2bf(e1) << 16);
    sum0 += e0; q0 = fmaf(e0, e0, q0);
    sum1 += e1; q1 = fmaf(e1, e1, q1);
    float sg0 = 1.f / (1.f + __expf(-e0));
    float sg1 = 1.f / (1.f + __expf(-e1));
    am0 = fmaf(bf2f_lo(db[1]), sg0, am0);
    am1 = fmaf(bf2f_hi(db[1]), sg1, am1);
    as0 += sg0; as1 += sg1;
  };

  int nmain = n & ~7;                         // 72 for n in {73,74}
  int4 mA[4], mB[4];
  unsigned ceA[4], ehA[4]; u32x2 dbA[4];
  unsigned ceB[4], ehB[4]; u32x2 dbB[4];
#pragma unroll
  for (int k = 0; k < 4; ++k) mA[k] = mp[k];
#pragma unroll
  for (int k = 0; k < 4; ++k) issue(mA[k], ceA[k], dbA[k], ehA[k]);
  for (int j = 0; j < nmain; j += 8) {
#pragma unroll
    for (int k = 0; k < 4; ++k) mB[k] = mp[j + 4 + k];
#pragma unroll
    for (int k = 0; k < 4; ++k) issue(mB[k], ceB[k], dbB[k], ehB[k]);
#pragma unroll
    for (int k = 0; k < 4; ++k) proc(mA[k].x, mA[k].z, ceA[k], dbA[k], ehA[k]);
    if (j + 8 < nmain) {
#pragma unroll
      for (int k = 0; k < 4; ++k) mA[k] = mp[j + 8 + k];
#pragma unroll
      for (int k = 0; k < 4; ++k) issue(mA[k], ceA[k], dbA[k], ehA[k]);
    }
#pragma unroll
    for (int k = 0; k < 4; ++k) proc(mB[k].x, mB[k].z, ceB[k], dbB[k], ehB[k]);
  }
  for (int j = nmain; j < n; ++j) {
    int4 m = mp[j];
    unsigned ce, eh; u32x2 db;
    issue(m, ce, db, eh);
    proc(m.x, m.z, ce, db, eh);
  }
  flush();

  atomicAdd(&s_sum[2 * lane], sum0);  atomicAdd(&s_sum[2 * lane + 1], sum1);
  atomicAdd(&s_sum2[2 * lane], q0);   atomicAdd(&s_sum2[2 * lane + 1], q1);
  __syncthreads();
  if (threadIdx.x < 128) {
    atomicAdd(stat_sum + threadIdx.x, s_sum[threadIdx.x]);
    atomicAdd(stat_sum2 + threadIdx.x, s_sum2[threadIdx.x]);
  }
}

// ---- K5: streaming BN apply on edges ----
__global__ __launch_bounds__(256) void bn_apply_e(
    const float* __restrict__ e, const unsigned short* __restrict__ enew,
    const float* __restrict__ scale, const float* __restrict__ shift,
    float* __restrict__ eout) {
  const size_t total8 = (size_t)N_EDGES * DIM / 8;
  for (size_t i = (size_t)blockIdx.x * blockDim.x + threadIdx.x; i < total8;
       i += (size_t)gridDim.x * blockDim.x) {
    int colbase = (int)((i * 8) & (DIM - 1));
    u32x4 en = ((const u32x4*)enew)[i];
    f32x4 e0 = ((const f32x4*)e)[2 * i];
    f32x4 e1 = ((const f32x4*)e)[2 * i + 1];
    f32x4 sc0 = *(const f32x4*)(scale + colbase);
    f32x4 sc1 = *(const f32x4*)(scale + colbase + 4);
    f32x4 sh0 = *(const f32x4*)(shift + colbase);
    f32x4 sh1 = *(const f32x4*)(shift + colbase + 4);
    float v[8];
#pragma unroll
    for (int j = 0; j < 4; ++j) {
      v[2 * j]     = bf2f_lo(en[j]);
      v[2 * j + 1] = bf2f_hi(en[j]);
    }
    f32x4 o0, o1;
#pragma unroll
    for (int j = 0; j < 4; ++j) {
      float y0 = v[j] * sc0[j] + sh0[j];
      o0[j] = e0[j] + fmaxf(y0, 0.f);
      float y1 = v[4 + j] * sc1[j] + sh1[j];
      o1[j] = e1[j] + fmaxf(y1, 0.f);
    }
    ((f32x4*)eout)[2 * i] = o0;
    ((f32x4*)eout)[2 * i + 1] = o1;
  }
}

// ---- node_pre: h_new pre-activation + BN-h stats ----
__global__ __launch_bounds__(256) void node_pre(
    const float* __restrict__ Ah, const float* __restrict__ acc_h,
    const float* __restrict__ acc_s, float* __restrict__ pre_out,
    float* __restrict__ stat_sum, float* __restrict__ stat_sum2) {
  __shared__ float s_sum[128], s_sum2[128];
  if (threadIdx.x < 128) { s_sum[threadIdx.x] = 0.f; s_sum2[threadIdx.x] = 0.f; }
  __syncthreads();
  const int total4 = N_NODES * DIM / 4;
  float ls[4] = {0, 0, 0, 0}, lq[4] = {0, 0, 0, 0};
  int colbase = (threadIdx.x & 31) * 4;
  for (int i = blockIdx.x * blockDim.x + threadIdx.x; i < total4;
       i += gridDim.x * blockDim.x) {
    f32x4 a = ((const f32x4*)Ah)[i];
    f32x4 mh = ((const f32x4*)acc_h)[i];
    f32x4 ms = ((const f32x4*)acc_s)[i];
    f32x4 p;
#pragma unroll
    for (int j = 0; j < 4; ++j) {
      p[j] = a[j] + mh[j] / (ms[j] + 1e-6f);
      ls[j] += p[j]; lq[j] += p[j] * p[j];
    }
    ((f32x4*)pre_out)[i] = p;
  }
#pragma unroll
  for (int j = 0; j < 4; ++j) {
    atomicAdd(&s_sum[colbase + j], ls[j]);
    atomicAdd(&s_sum2[colbase + j], lq[j]);
  }
  __syncthreads();
  if (threadIdx.x < 128) {
    atomicAdd(stat_sum + threadIdx.x, s_sum[threadIdx.x]);
    atomicAdd(stat_sum2 + threadIdx.x, s_sum2[threadIdx.x]);
  }
}

__global__ void finalize_stats(const float* __restrict__ sum, const float* __restrict__ sum2,
                               const float* __restrict__ gamma, const float* __restrict__ beta,
                               float count, float* __restrict__ scale, float* __restrict__ shift) {
  int c = threadIdx.x;
  if (c < 128) {
    float mu = sum[c] / count;
    float var = sum2[c] / count - mu * mu;
    float inv = rsqrtf(var + 1e-5f);
    float sc = gamma[c] * inv;
    scale[c] = sc;
    shift[c] = beta[c] - mu * sc;
  }
}

__global__ __launch_bounds__(256) void node_final(
    const float* __restrict__ h, float* __restrict__ hout,
    const float* __restrict__ scale, const float* __restrict__ shift) {
  const int total4 = N_NODES * DIM / 4;
  for (int i = blockIdx.x * blockDim.x + threadIdx.x; i < total4;
       i += gridDim.x * blockDim.x) {
    f32x4 p = ((const f32x4*)hout)[i];
    f32x4 hv = ((const f32x4*)h)[i];
    f32x4 sc4 = ((const f32x4*)scale)[i & 31];
    f32x4 sh4 = ((const f32x4*)shift)[i & 31];
    f32x4 o;
#pragma unroll
    for (int j = 0; j < 4; ++j) {
      float y = p[j] * sc4[j] + sh4[j];
      o[j] = hv[j] + fmaxf(y, 0.f);
    }
    ((f32x4*)hout)[i] = o;
  }
}

extern "C" void kernel_launch(void* const* d_in, const int* in_sizes, int n_in,
                              void* d_out, int out_size, void* d_ws, size_t ws_size,
                              hipStream_t stream) {
  const float* h   = (const float*)d_in[0];
  const float* e   = (const float*)d_in[1];
  const int*   src = (const int*)d_in[2];
  const int*   dst = (const int*)d_in[3];
  const float* Aw = (const float*)d_in[4];  const float* Ab = (const float*)d_in[5];
  const float* Bw = (const float*)d_in[6];  const float* Bb = (const float*)d_in[7];
  const float* Cw = (const float*)d_in[8];  const float* Cb = (const float*)d_in[9];
  const float* Dw = (const float*)d_in[10]; const float* Db = (const float*)d_in[11];
  const float* Ew = (const float*)d_in[12]; const float* Eb = (const float*)d_in[13];
  const float* bn_h_g = (const float*)d_in[14]; const float* bn_h_b = (const float*)d_in[15];
  const float* bn_e_g = (const float*)d_in[16]; const float* bn_e_b = (const float*)d_in[17];

  const size_t ND_F32 = (size_t)N_NODES * DIM * 4;   // 25.6 MB
  const size_t ND_BF  = (size_t)N_NODES * DIM * 2;   // 12.8 MB
  const size_t ED_BF  = (size_t)N_EDGES * DIM * 2;   // 153.6 MB
  char* ws = (char*)d_ws;
  unsigned short* wbf = (unsigned short*)ws;          // 163840 B
  size_t off = 163840;
  float* Ah = (float*)(ws + off);                   off += ND_F32;
  unsigned short* DB = (unsigned short*)(ws + off); off += 2 * ND_BF;  // interleaved D|B
  unsigned short* Eh = (unsigned short*)(ws + off); off += ND_BF;
  unsigned short* Ce = (unsigned short*)(ws + off);   off += ED_BF;
  unsigned short* enew = (unsigned short*)(ws + off); off += ED_BF;
  // ---- zeroed region ----
  char* zero_base = ws + off;
  float* acc_h = (float*)(ws + off); off += ND_F32;
  float* acc_s = (float*)(ws + off); off += ND_F32;
  int* counts  = (int*)(ws + off);   off += 200000;
  int* cursor  = (int*)(ws + off);   off += 200000;
  float* stats = (float*)(ws + off); off += 4096;
  size_t zero_bytes = (size_t)(ws + off - zero_base);
  // ---- not zeroed ----
  int* offsets = (int*)(ws + off);   off += 200064;
  int4* meta   = (int4*)(ws + off);  off += (size_t)N_EDGES * 16;

  float* e_sum = stats,        *e_sum2 = stats + 128;
  float* h_sum = stats + 256,  *h_sum2 = stats + 384;
  float* scale_e = stats + 512, *shift_e = stats + 640;
  float* scale_h = stats + 768, *shift_h = stats + 896;

  float* hout = (float*)d_out;
  float* eout = (float*)d_out + (size_t)N_NODES * DIM;

  hipMemsetAsync(zero_base, 0, zero_bytes, stream);

  setup_kernel<<<(N_EDGES + 255) / 256, 256, 0, stream>>>(Aw, Bw, Cw, Dw, Ew, wbf,
      dst, counts);
  scan_kernel<<<1, 1024, 0, stream>>>(counts, offsets);
  bucket_kernel<<<(N_EDGES + 255) / 256, 256, 0, stream>>>(src, dst, offsets, cursor, meta);
  node_gemm<<<(N_NODES + 63) / 64, 256, 0, stream>>>(h, wbf, Ab, Bb, Db, Eb, Ah, DB, Eh);
  ce_gemm<<<CE_BLOCKS, 256, 0, stream>>>(e, wbf, Cb, Ce);
  edge_gather<<<GATHER_BLOCKS, 256, 0, stream>>>(meta, DB, Eh, Ce, enew,
      acc_h, acc_s, e_sum, e_sum2);
  finalize_stats<<<1, 128, 0, stream>>>(e_sum, e_sum2, bn_e_g, bn_e_b, (float)N_EDGES,
      scale_e, shift_e);
  node_pre<<<1024, 256, 0, stream>>>(Ah, acc_h, acc_s, hout, h_sum, h_sum2);
  finalize_stats<<<1, 128, 0, stream>>>(h_sum, h_sum2, bn_h_g, bn_h_b, (float)N_NODES,
      scale_h, shift_h);
  bn_apply_e<<<2048, 256, 0, stream>>>(e, enew, scale_e, shift_e, eout);
  node_final<<<1024, 256, 0, stream>>>(h, hout, scale_h, shift_h);
}

// Round 6
// 704.272 us; speedup vs baseline: 1.6537x; 1.0290x over previous
//
#include <hip/hip_runtime.h>
#include <stdint.h>

#define N_NODES 50000
#define N_EDGES 600000
#define DIM 128
#define N_TILES (N_EDGES / 64)   // 9375
#define NODE_BLOCKS 782          // ceil(50000/64)
#define CE_BLOCKS 1875           // 9375 / 5 tiles each, exact
#define GATHER_BLOCKS 2048       // 8192 waves
#define NF_BLOCKS 256            // node_final part of apply_fused
#define BN_BLOCKS 3840           // bn_apply part of apply_fused

typedef __attribute__((ext_vector_type(8))) short bf16x8;
typedef __attribute__((ext_vector_type(4))) float f32x4;
typedef __attribute__((ext_vector_type(4))) unsigned int u32x4;
typedef __attribute__((ext_vector_type(2))) unsigned int u32x2;

__device__ inline unsigned short f2bf(float f) {
  unsigned u = __builtin_bit_cast(unsigned, f);
  unsigned r = 0x7fffu + ((u >> 16) & 1u);
  return (unsigned short)((u + r) >> 16);
}
__device__ inline float bf2f_lo(unsigned p) { return __builtin_bit_cast(float, p << 16); }
__device__ inline float bf2f_hi(unsigned p) { return __builtin_bit_cast(float, p & 0xffff0000u); }

// ---- LDS staging (swizzled bf16 tiles, row stride 256 B) ----
__device__ inline void stage_pack_store(char* lds, int row, int f, f32x4 v0, f32x4 v1) {
  u32x4 q;
  q[0] = (unsigned)f2bf(v0[0]) | ((unsigned)f2bf(v0[1]) << 16);
  q[1] = (unsigned)f2bf(v0[2]) | ((unsigned)f2bf(v0[3]) << 16);
  q[2] = (unsigned)f2bf(v1[0]) | ((unsigned)f2bf(v1[1]) << 16);
  q[3] = (unsigned)f2bf(v1[2]) | ((unsigned)f2bf(v1[3]) << 16);
  int byte = (f * 16) ^ ((row & 7) << 4);
  *(u32x4*)(lds + row * 256 + byte) = q;
}

__device__ inline void stage_tile_f32(const float* __restrict__ src, int row0,
                                      int nvalid, char* lds) {
#pragma unroll
  for (int it = 0; it < 4; ++it) {
    int c = it * 256 + threadIdx.x;
    int row = c >> 4, f = c & 15;
    f32x4 v0 = {0, 0, 0, 0}, v1 = {0, 0, 0, 0};
    if (row < nvalid) {
      const f32x4* p = (const f32x4*)(src + (size_t)(row0 + row) * DIM + f * 8);
      v0 = p[0]; v1 = p[1];
    }
    stage_pack_store(lds, row, f, v0, v1);
  }
}

__device__ inline void stage_w(const unsigned short* __restrict__ wbf, char* lds) {
#pragma unroll
  for (int it = 0; it < 8; ++it) {
    int c = it * 256 + threadIdx.x;
    int row = c >> 4, f = c & 15;
    u32x4 q = *(const u32x4*)(wbf + row * 128 + f * 8);
    int byte = (f * 16) ^ ((row & 7) << 4);
    *(u32x4*)(lds + row * 256 + byte) = q;
  }
}

__device__ inline bf16x8 read_frag(const char* lds, int row, int ks, int lane) {
  int byte = ks * 64 + ((lane >> 4) * 16);
  byte ^= ((row & 7) << 4);
  return *(const bf16x8*)(lds + row * 256 + byte);
}

// ---- K0: weight conversion + dst histogram (merged) ----
__global__ void setup_kernel(const float* __restrict__ a, const float* __restrict__ b,
                             const float* __restrict__ c, const float* __restrict__ d,
                             const float* __restrict__ e5, unsigned short* __restrict__ out,
                             const int* __restrict__ dst, int* __restrict__ counts) {
  int i = blockIdx.x * 256 + threadIdx.x;
  if (i < 5 * 16384) {
    int m = i >> 14, k = i & 16383;
    const float* p = (m == 0) ? a : (m == 1) ? b : (m == 2) ? c : (m == 3) ? d : e5;
    out[i] = f2bf(p[k]);
  }
  if (i < N_EDGES) atomicAdd(&counts[dst[i]], 1);
}

__global__ __launch_bounds__(1024) void scan_kernel(const int* __restrict__ counts,
                                                    int* __restrict__ offsets) {
  __shared__ int part[1024];
  const int CHK = 49;
  int t = threadIdx.x;
  int base = t * CHK;
  int s = 0;
  for (int k = 0; k < CHK; ++k) {
    int i = base + k;
    if (i < N_NODES) s += counts[i];
  }
  part[t] = s;
  __syncthreads();
  for (int off = 1; off < 1024; off <<= 1) {
    int v = part[t];
    int u = (t >= off) ? part[t - off] : 0;
    __syncthreads();
    part[t] = v + u;
    __syncthreads();
  }
  int run = (t == 0) ? 0 : part[t - 1];
  for (int k = 0; k < CHK; ++k) {
    int i = base + k;
    if (i < N_NODES) { offsets[i] = run; run += counts[i]; }
  }
  if (t == 1023) offsets[N_NODES] = run;
}

// meta[p] = (edge, src, dst, 0) in dst-sorted order
__global__ void bucket_kernel(const int* __restrict__ src, const int* __restrict__ dst,
                              const int* __restrict__ offsets, int* __restrict__ cursor,
                              int4* __restrict__ meta) {
  int i = blockIdx.x * 256 + threadIdx.x;
  if (i < N_EDGES) {
    int d = dst[i];
    int p = offsets[d] + atomicAdd(&cursor[d], 1);
    meta[p] = make_int4(i, src[i], d, 0);
  }
}

// ---- K1: fused GEMMs.
// Blocks [0, NODE_BLOCKS): node GEMMs (A,B,D,E). Ah fp32; DB interleaved bf16; Eh bf16.
// Blocks [NODE_BLOCKS, +CE_BLOCKS): Ce = e @ C^T + Cb (bf16), 5 tiles each,
// register-staged pipeline (issue next tile's loads during current MFMA).
__global__ __launch_bounds__(256) void fused_gemm(
    const float* __restrict__ h, const float* __restrict__ e,
    const unsigned short* __restrict__ wbf,
    const float* __restrict__ Ab, const float* __restrict__ Bb,
    const float* __restrict__ Db, const float* __restrict__ Eb,
    const float* __restrict__ Cb,
    float* __restrict__ Ah, unsigned short* __restrict__ DB,
    unsigned short* __restrict__ Eh, unsigned short* __restrict__ Ce) {
  __shared__ __align__(16) char lds_x[64 * 256];
  __shared__ __align__(16) char lds_w[128 * 256];
  int lane = threadIdx.x & 63, w = threadIdx.x >> 6;
  int prow = w * 16 + (lane & 15);

  if (blockIdx.x < NODE_BLOCKS) {
    int tile = blockIdx.x * 64;
    int nvalid = N_NODES - tile; if (nvalid > 64) nvalid = 64;
    stage_tile_f32(h, tile, nvalid, lds_x);
    __syncthreads();
    bf16x8 a[4];
#pragma unroll
    for (int ks = 0; ks < 4; ++ks) a[ks] = read_frag(lds_x, prow, ks, lane);

    const int wmat[4] = {0, 1, 3, 4};           // A,B,D,E
    const float* const biases[4] = {Ab, Bb, Db, Eb};
#pragma unroll
    for (int m = 0; m < 4; ++m) {
      __syncthreads();
      stage_w(wbf + wmat[m] * 16384, lds_w);
      __syncthreads();
      f32x4 acc[8] = {};
#pragma unroll
      for (int ct = 0; ct < 8; ++ct) {
#pragma unroll
        for (int ks = 0; ks < 4; ++ks) {
          bf16x8 b = read_frag(lds_w, ct * 16 + (lane & 15), ks, lane);
          acc[ct] = __builtin_amdgcn_mfma_f32_16x16x32_bf16(a[ks], b, acc[ct], 0, 0, 0);
        }
      }
      const float* bias = biases[m];
#pragma unroll
      for (int ct = 0; ct < 8; ++ct) {
        int col = ct * 16 + (lane & 15);
        float bv = bias[col];
#pragma unroll
        for (int j = 0; j < 4; ++j) {
          int r = tile + w * 16 + (lane >> 4) * 4 + j;
          if (r < N_NODES) {
            float v = acc[ct][j] + bv;
            if (m == 0) Ah[(size_t)r * DIM + col] = v;
            else if (m == 1) DB[(size_t)r * 256 + 4 * (col >> 1) + 2 + (col & 1)] = f2bf(v);
            else if (m == 2) DB[(size_t)r * 256 + 4 * (col >> 1) + (col & 1)] = f2bf(v);
            else Eh[(size_t)r * DIM + col] = f2bf(v);
          }
        }
      }
    }
  } else {
    stage_w(wbf + 2 * 16384, lds_w);
    int t0 = blockIdx.x - NODE_BLOCKS;
    int srow = threadIdx.x >> 4, sf = threadIdx.x & 15;   // staging row/chunk
    f32x4 r0[4], r1[4];
    auto gload = [&](int tile) {
#pragma unroll
      for (int it = 0; it < 4; ++it) {
        const f32x4* p = (const f32x4*)(e + (size_t)(tile * 64 + it * 16 + srow) * DIM + sf * 8);
        r0[it] = p[0]; r1[it] = p[1];
      }
    };
    auto lstore = [&]() {
#pragma unroll
      for (int it = 0; it < 4; ++it)
        stage_pack_store(lds_x, it * 16 + srow, sf, r0[it], r1[it]);
    };
    gload(t0);
#pragma unroll 1
    for (int i = 0; i < 5; ++i) {
      int tile = t0 + i * CE_BLOCKS;
      __syncthreads();                  // lds_x free (prev MFMA reads done); lds_w staged
      lstore();
      if (i < 4) gload(t0 + (i + 1) * CE_BLOCKS);
      __syncthreads();                  // lds_x ready
      bf16x8 a[4];
#pragma unroll
      for (int ks = 0; ks < 4; ++ks) a[ks] = read_frag(lds_x, prow, ks, lane);
      f32x4 acc[8] = {};
#pragma unroll
      for (int ct = 0; ct < 8; ++ct) {
#pragma unroll
        for (int ks = 0; ks < 4; ++ks) {
          bf16x8 b = read_frag(lds_w, ct * 16 + (lane & 15), ks, lane);
          acc[ct] = __builtin_amdgcn_mfma_f32_16x16x32_bf16(a[ks], b, acc[ct], 0, 0, 0);
        }
      }
#pragma unroll
      for (int ct = 0; ct < 8; ++ct) {
        int col = ct * 16 + (lane & 15);
        float bv = Cb[col];
#pragma unroll
        for (int j = 0; j < 4; ++j) {
          int r = tile * 64 + w * 16 + (lane >> 4) * 4 + j;
          Ce[(size_t)r * DIM + col] = f2bf(acc[ct][j] + bv);
        }
      }
    }
  }
}

// ---- K3: gather/scatter over dst-sorted edges (unchanged from r5) ----
__global__ __launch_bounds__(256, 8) void edge_gather(
    const int4* __restrict__ meta,
    const unsigned short* __restrict__ DB, const unsigned short* __restrict__ Eh,
    const unsigned short* __restrict__ Ce, unsigned short* __restrict__ enew,
    float* __restrict__ acc_h, float* __restrict__ acc_s,
    float* __restrict__ stat_sum, float* __restrict__ stat_sum2) {
  __shared__ float s_sum[128], s_sum2[128];
  if (threadIdx.x < 128) { s_sum[threadIdx.x] = 0.f; s_sum2[threadIdx.x] = 0.f; }
  __syncthreads();
  int lane = threadIdx.x & 63;
  int w = __builtin_amdgcn_readfirstlane(threadIdx.x >> 6);
  int wid = blockIdx.x * 4 + w;
  int base = (int)(((long long)wid * N_EDGES) >> 13);       // /8192 waves
  int end  = (int)(((long long)(wid + 1) * N_EDGES) >> 13);
  int n = end - base;                                       // 73 or 74
  const int4* mp = meta + base;

  float sum0 = 0.f, sum1 = 0.f, q0 = 0.f, q1 = 0.f;
  float am0 = 0.f, am1 = 0.f, as0 = 0.f, as1 = 0.f;
  int cur_d = mp[0].z;

  auto issue = [&](const int4& m, unsigned& ce, u32x2& db, unsigned& eh) {
    ce = *(const unsigned*)(Ce + (size_t)m.x * DIM + 2 * lane);
    db = *(const u32x2*)(DB + (size_t)m.y * 256 + 4 * lane);
    eh = *(const unsigned*)(Eh + (size_t)m.z * DIM + 2 * lane);
  };
  auto flush = [&]() {
    size_t o = (size_t)cur_d * DIM + 2 * lane;
    atomicAdd(acc_h + o, am0); atomicAdd(acc_h + o + 1, am1);
    atomicAdd(acc_s + o, as0); atomicAdd(acc_s + o + 1, as1);
    am0 = am1 = as0 = as1 = 0.f;
  };
  auto proc = [&](int pe, int d, unsigned ce, u32x2 db, unsigned eh) {
    if (d != cur_d) { flush(); cur_d = d; }
    float e0 = bf2f_lo(ce) + bf2f_lo(db[0]) + bf2f_lo(eh);
    float e1 = bf2f_hi(ce) + bf2f_hi(db[0]) + bf2f_hi(eh);
    *(unsigned*)(enew + (size_t)pe * DIM + 2 * lane) =
        (unsigned)f2bf(e0) | ((unsigned)f2bf(e1) << 16);
    sum0 += e0; q0 = fmaf(e0, e0, q0);
    sum1 += e1; q1 = fmaf(e1, e1, q1);
    float sg0 = 1.f / (1.f + __expf(-e0));
    float sg1 = 1.f / (1.f + __expf(-e1));
    am0 = fmaf(bf2f_lo(db[1]), sg0, am0);
    am1 = fmaf(bf2f_hi(db[1]), sg1, am1);
    as0 += sg0; as1 += sg1;
  };

  int nmain = n & ~7;
  int4 mA[4], mB[4];
  unsigned ceA[4], ehA[4]; u32x2 dbA[4];
  unsigned ceB[4], ehB[4]; u32x2 dbB[4];
#pragma unroll
  for (int k = 0; k < 4; ++k) mA[k] = mp[k];
#pragma unroll
  for (int k = 0; k < 4; ++k) issue(mA[k], ceA[k], dbA[k], ehA[k]);
  for (int j = 0; j < nmain; j += 8) {
#pragma unroll
    for (int k = 0; k < 4; ++k) mB[k] = mp[j + 4 + k];
#pragma unroll
    for (int k = 0; k < 4; ++k) issue(mB[k], ceB[k], dbB[k], ehB[k]);
#pragma unroll
    for (int k = 0; k < 4; ++k) proc(mA[k].x, mA[k].z, ceA[k], dbA[k], ehA[k]);
    if (j + 8 < nmain) {
#pragma unroll
      for (int k = 0; k < 4; ++k) mA[k] = mp[j + 8 + k];
#pragma unroll
      for (int k = 0; k < 4; ++k) issue(mA[k], ceA[k], dbA[k], ehA[k]);
    }
#pragma unroll
    for (int k = 0; k < 4; ++k) proc(mB[k].x, mB[k].z, ceB[k], dbB[k], ehB[k]);
  }
  for (int j = nmain; j < n; ++j) {
    int4 m = mp[j];
    unsigned ce, eh; u32x2 db;
    issue(m, ce, db, eh);
    proc(m.x, m.z, ce, db, eh);
  }
  flush();

  atomicAdd(&s_sum[2 * lane], sum0);  atomicAdd(&s_sum[2 * lane + 1], sum1);
  atomicAdd(&s_sum2[2 * lane], q0);   atomicAdd(&s_sum2[2 * lane + 1], q1);
  __syncthreads();
  if (threadIdx.x < 128) {
    atomicAdd(stat_sum + threadIdx.x, s_sum[threadIdx.x]);
    atomicAdd(stat_sum2 + threadIdx.x, s_sum2[threadIdx.x]);
  }
}

// ---- node_pre: h_new pre-activation + BN-h stats ----
__global__ __launch_bounds__(256) void node_pre(
    const float* __restrict__ Ah, const float* __restrict__ acc_h,
    const float* __restrict__ acc_s, float* __restrict__ pre_out,
    float* __restrict__ stat_sum, float* __restrict__ stat_sum2) {
  __shared__ float s_sum[128], s_sum2[128];
  if (threadIdx.x < 128) { s_sum[threadIdx.x] = 0.f; s_sum2[threadIdx.x] = 0.f; }
  __syncthreads();
  const int total4 = N_NODES * DIM / 4;
  float ls[4] = {0, 0, 0, 0}, lq[4] = {0, 0, 0, 0};
  int colbase = (threadIdx.x & 31) * 4;
  for (int i = blockIdx.x * blockDim.x + threadIdx.x; i < total4;
       i += gridDim.x * blockDim.x) {
    f32x4 a = ((const f32x4*)Ah)[i];
    f32x4 mh = ((const f32x4*)acc_h)[i];
    f32x4 ms = ((const f32x4*)acc_s)[i];
    f32x4 p;
#pragma unroll
    for (int j = 0; j < 4; ++j) {
      p[j] = a[j] + mh[j] / (ms[j] + 1e-6f);
      ls[j] += p[j]; lq[j] += p[j] * p[j];
    }
    ((f32x4*)pre_out)[i] = p;
  }
#pragma unroll
  for (int j = 0; j < 4; ++j) {
    atomicAdd(&s_sum[colbase + j], ls[j]);
    atomicAdd(&s_sum2[colbase + j], lq[j]);
  }
  __syncthreads();
  if (threadIdx.x < 128) {
    atomicAdd(stat_sum + threadIdx.x, s_sum[threadIdx.x]);
    atomicAdd(stat_sum2 + threadIdx.x, s_sum2[threadIdx.x]);
  }
}

// ---- finalize both BN scale/shift in one 1-block launch ----
__global__ void finalize_both(const float* __restrict__ stats,
                              const float* __restrict__ bn_e_g, const float* __restrict__ bn_e_b,
                              const float* __restrict__ bn_h_g, const float* __restrict__ bn_h_b,
                              float* __restrict__ scale_e, float* __restrict__ shift_e,
                              float* __restrict__ scale_h, float* __restrict__ shift_h) {
  int t = threadIdx.x;
  if (t < 128) {
    float mu = stats[t] / (float)N_EDGES;
    float var = stats[128 + t] / (float)N_EDGES - mu * mu;
    float inv = rsqrtf(var + 1e-5f);
    float sc = bn_e_g[t] * inv;
    scale_e[t] = sc;
    shift_e[t] = bn_e_b[t] - mu * sc;
  } else {
    int c = t - 128;
    float mu = stats[256 + c] / (float)N_NODES;
    float var = stats[384 + c] / (float)N_NODES - mu * mu;
    float inv = rsqrtf(var + 1e-5f);
    float sc = bn_h_g[c] * inv;
    scale_h[c] = sc;
    shift_h[c] = bn_h_b[c] - mu * sc;
  }
}

// ---- apply_fused: blocks [0,NF): h_out = h + relu(pre*sc+sh) (in place on hout);
//      blocks [NF, NF+BN): e_out = e + relu(enew*sc+sh), 16 floats/thread ----
__global__ __launch_bounds__(256) void apply_fused(
    const float* __restrict__ e, const unsigned short* __restrict__ enew,
    const float* __restrict__ scale_e, const float* __restrict__ shift_e,
    float* __restrict__ eout,
    const float* __restrict__ h, float* __restrict__ hout,
    const float* __restrict__ scale_h, const float* __restrict__ shift_h) {
  if (blockIdx.x < NF_BLOCKS) {
    const int total4 = N_NODES * DIM / 4;
    for (int i = blockIdx.x * 256 + threadIdx.x; i < total4; i += NF_BLOCKS * 256) {
      f32x4 p = ((const f32x4*)hout)[i];
      f32x4 hv = ((const f32x4*)h)[i];
      f32x4 sc4 = ((const f32x4*)scale_h)[i & 31];
      f32x4 sh4 = ((const f32x4*)shift_h)[i & 31];
      f32x4 o;
#pragma unroll
      for (int j = 0; j < 4; ++j) {
        float y = p[j] * sc4[j] + sh4[j];
        o[j] = hv[j] + fmaxf(y, 0.f);
      }
      ((f32x4*)hout)[i] = o;
    }
  } else {
    int bid = blockIdx.x - NF_BLOCKS;
    const size_t total16 = (size_t)N_EDGES * DIM / 16;
    for (size_t i = (size_t)bid * 256 + threadIdx.x; i < total16;
         i += (size_t)BN_BLOCKS * 256) {
      int colbase = (int)((i * 16) & (DIM - 1));
      u32x4 en0 = ((const u32x4*)enew)[2 * i];
      u32x4 en1 = ((const u32x4*)enew)[2 * i + 1];
      f32x4 e0 = ((const f32x4*)e)[4 * i];
      f32x4 e1 = ((const f32x4*)e)[4 * i + 1];
      f32x4 e2 = ((const f32x4*)e)[4 * i + 2];
      f32x4 e3 = ((const f32x4*)e)[4 * i + 3];
      f32x4 sc0 = *(const f32x4*)(scale_e + colbase);
      f32x4 sc1 = *(const f32x4*)(scale_e + colbase + 4);
      f32x4 sc2 = *(const f32x4*)(scale_e + colbase + 8);
      f32x4 sc3 = *(const f32x4*)(scale_e + colbase + 12);
      f32x4 sh0 = *(const f32x4*)(shift_e + colbase);
      f32x4 sh1 = *(const f32x4*)(shift_e + colbase + 4);
      f32x4 sh2 = *(const f32x4*)(shift_e + colbase + 8);
      f32x4 sh3 = *(const f32x4*)(shift_e + colbase + 12);
      float v[16];
#pragma unroll
      for (int j = 0; j < 4; ++j) {
        v[2 * j]     = bf2f_lo(en0[j]);
        v[2 * j + 1] = bf2f_hi(en0[j]);
        v[8 + 2 * j]     = bf2f_lo(en1[j]);
        v[8 + 2 * j + 1] = bf2f_hi(en1[j]);
      }
      f32x4 o0, o1, o2, o3;
#pragma unroll
      for (int j = 0; j < 4; ++j) {
        o0[j] = e0[j] + fmaxf(v[j] * sc0[j] + sh0[j], 0.f);
        o1[j] = e1[j] + fmaxf(v[4 + j] * sc1[j] + sh1[j], 0.f);
        o2[j] = e2[j] + fmaxf(v[8 + j] * sc2[j] + sh2[j], 0.f);
        o3[j] = e3[j] + fmaxf(v[12 + j] * sc3[j] + sh3[j], 0.f);
      }
      ((f32x4*)eout)[4 * i] = o0;
      ((f32x4*)eout)[4 * i + 1] = o1;
      ((f32x4*)eout)[4 * i + 2] = o2;
      ((f32x4*)eout)[4 * i + 3] = o3;
    }
  }
}

extern "C" void kernel_launch(void* const* d_in, const int* in_sizes, int n_in,
                              void* d_out, int out_size, void* d_ws, size_t ws_size,
                              hipStream_t stream) {
  const float* h   = (const float*)d_in[0];
  const float* e   = (const float*)d_in[1];
  const int*   src = (const int*)d_in[2];
  const int*   dst = (const int*)d_in[3];
  const float* Aw = (const float*)d_in[4];  const float* Ab = (const float*)d_in[5];
  const float* Bw = (const float*)d_in[6];  const float* Bb = (const float*)d_in[7];
  const float* Cw = (const float*)d_in[8];  const float* Cb = (const float*)d_in[9];
  const float* Dw = (const float*)d_in[10]; const float* Db = (const float*)d_in[11];
  const float* Ew = (const float*)d_in[12]; const float* Eb = (const float*)d_in[13];
  const float* bn_h_g = (const float*)d_in[14]; const float* bn_h_b = (const float*)d_in[15];
  const float* bn_e_g = (const float*)d_in[16]; const float* bn_e_b = (const float*)d_in[17];

  const size_t ND_F32 = (size_t)N_NODES * DIM * 4;   // 25.6 MB
  const size_t ND_BF  = (size_t)N_NODES * DIM * 2;   // 12.8 MB
  const size_t ED_BF  = (size_t)N_EDGES * DIM * 2;   // 153.6 MB
  char* ws = (char*)d_ws;
  unsigned short* wbf = (unsigned short*)ws;          // 163840 B
  size_t off = 163840;
  float* Ah = (float*)(ws + off);                   off += ND_F32;
  unsigned short* DB = (unsigned short*)(ws + off); off += 2 * ND_BF;  // interleaved D|B
  unsigned short* Eh = (unsigned short*)(ws + off); off += ND_BF;
  unsigned short* Ce = (unsigned short*)(ws + off);   off += ED_BF;
  unsigned short* enew = (unsigned short*)(ws + off); off += ED_BF;
  // ---- zeroed region ----
  char* zero_base = ws + off;
  float* acc_h = (float*)(ws + off); off += ND_F32;
  float* acc_s = (float*)(ws + off); off += ND_F32;
  int* counts  = (int*)(ws + off);   off += 200000;
  int* cursor  = (int*)(ws + off);   off += 200000;
  float* stats = (float*)(ws + off); off += 4096;
  size_t zero_bytes = (size_t)(ws + off - zero_base);
  // ---- not zeroed ----
  int* offsets = (int*)(ws + off);   off += 200064;
  int4* meta   = (int4*)(ws + off);  off += (size_t)N_EDGES * 16;

  float* e_sum = stats,        *e_sum2 = stats + 128;
  float* h_sum = stats + 256,  *h_sum2 = stats + 384;
  float* scale_e = stats + 512, *shift_e = stats + 640;
  float* scale_h = stats + 768, *shift_h = stats + 896;

  float* hout = (float*)d_out;
  float* eout = (float*)d_out + (size_t)N_NODES * DIM;

  hipMemsetAsync(zero_base, 0, zero_bytes, stream);

  setup_kernel<<<(N_EDGES + 255) / 256, 256, 0, stream>>>(Aw, Bw, Cw, Dw, Ew, wbf,
      dst, counts);
  scan_kernel<<<1, 1024, 0, stream>>>(counts, offsets);
  bucket_kernel<<<(N_EDGES + 255) / 256, 256, 0, stream>>>(src, dst, offsets, cursor, meta);
  fused_gemm<<<NODE_BLOCKS + CE_BLOCKS, 256, 0, stream>>>(h, e, wbf, Ab, Bb, Db, Eb, Cb,
      Ah, DB, Eh, Ce);
  edge_gather<<<GATHER_BLOCKS, 256, 0, stream>>>(meta, DB, Eh, Ce, enew,
      acc_h, acc_s, e_sum, e_sum2);
  node_pre<<<1024, 256, 0, stream>>>(Ah, acc_h, acc_s, hout, h_sum, h_sum2);
  finalize_both<<<1, 256, 0, stream>>>(stats, bn_e_g, bn_e_b, bn_h_g, bn_h_b,
      scale_e, shift_e, scale_h, shift_h);
  apply_fused<<<NF_BLOCKS + BN_BLOCKS, 256, 0, stream>>>(e, enew, scale_e, shift_e, eout,
      h, hout, scale_h, shift_h);
}